// Round 1
// baseline (945.411 us; speedup 1.0000x reference)
//
#include <hip/hip_runtime.h>
#include <hip/hip_bf16.h>

#define N_NODES 50000
#define E_EDGES 800000
#define IN_DIM  256
#define HID     128
#define OUT_DIM 16

// ---------------- degree / norm precompute ----------------

__global__ void deg_init(float* __restrict__ deg, int n) {
    int i = blockIdx.x * blockDim.x + threadIdx.x;
    if (i < n) deg[i] = 1.0f;  // self loop contributes 1
}

__global__ void deg_count(const int* __restrict__ dst, float* __restrict__ deg, int e) {
    int i = blockIdx.x * blockDim.x + threadIdx.x;
    if (i < e) atomicAdd(&deg[dst[i]], 1.0f);
}

__global__ void deg_rsqrt(float* __restrict__ deg, int n) {
    int i = blockIdx.x * blockDim.x + threadIdx.x;
    if (i < n) deg[i] = rsqrtf(deg[i]);  // deg >= 1 always (self loop)
}

__global__ void edge_norm(const int* __restrict__ src, const int* __restrict__ dst,
                          const float* __restrict__ dinv, float* __restrict__ norm, int e) {
    int i = blockIdx.x * blockDim.x + threadIdx.x;
    if (i < e) norm[i] = dinv[src[i]] * dinv[dst[i]];
}

// ---------------- dense transform: h = x @ W ----------------
// one thread per (node, out_feature); K-loop unrolled x4 with float4 x loads.
template<int K, int M>
__global__ void gemm_kernel(const float* __restrict__ x, const float* __restrict__ W,
                            float* __restrict__ h, int n) {
    int idx = blockIdx.x * blockDim.x + threadIdx.x;
    if (idx >= n * M) return;
    int node = idx / M;
    int f    = idx % M;
    const float* xr = x + (size_t)node * K;
    float acc = 0.0f;
#pragma unroll 4
    for (int k = 0; k < K; k += 4) {
        float4 xv = *(const float4*)(xr + k);
        acc += xv.x * W[(k + 0) * M + f];
        acc += xv.y * W[(k + 1) * M + f];
        acc += xv.z * W[(k + 2) * M + f];
        acc += xv.w * W[(k + 3) * M + f];
    }
    h[idx] = acc;
}

// ---------------- aggregation ----------------
// init: out = bias + self-loop term (h[i] * dinv[i]^2); removes those atomics.
template<int M>
__global__ void agg_init(const float* __restrict__ h, const float* __restrict__ dinv,
                         const float* __restrict__ b, float* __restrict__ out, int n) {
    int idx = blockIdx.x * blockDim.x + threadIdx.x;
    if (idx >= n * M) return;
    int node = idx / M;
    int f    = idx % M;
    float di = dinv[node];
    out[idx] = b[f] + h[idx] * di * di;
}

// edges: thread per (edge, feature). Consecutive lanes = consecutive features
// of one dst row -> coalesced atomic bursts; src/dst/norm broadcast per row.
template<int M>
__global__ void agg_edges(const int* __restrict__ src, const int* __restrict__ dst,
                          const float* __restrict__ norm, const float* __restrict__ h,
                          float* __restrict__ out, int e) {
    int idx = blockIdx.x * blockDim.x + threadIdx.x;
    if (idx >= e * M) return;
    int ed = idx / M;
    int f  = idx % M;
    int s  = src[ed];
    int d  = dst[ed];
    float v = h[(size_t)s * M + f] * norm[ed];
    atomicAdd(&out[(size_t)d * M + f], v);
}

__global__ void relu_kernel(float* __restrict__ a, int total) {
    int i = blockIdx.x * blockDim.x + threadIdx.x;
    if (i < total) a[i] = fmaxf(a[i], 0.0f);
}

// ---------------- log_softmax over 16 features, in place ----------------
__global__ void log_softmax16(float* __restrict__ out, int n) {
    int i = blockIdx.x * blockDim.x + threadIdx.x;
    if (i >= n) return;
    float* row = out + (size_t)i * 16;
    float4 v[4];
#pragma unroll
    for (int j = 0; j < 4; ++j) v[j] = *(float4*)(row + 4 * j);
    float m = -1e30f;
#pragma unroll
    for (int j = 0; j < 4; ++j) {
        m = fmaxf(m, fmaxf(fmaxf(v[j].x, v[j].y), fmaxf(v[j].z, v[j].w)));
    }
    float s = 0.0f;
#pragma unroll
    for (int j = 0; j < 4; ++j) {
        s += expf(v[j].x - m) + expf(v[j].y - m) + expf(v[j].z - m) + expf(v[j].w - m);
    }
    float lse = m + logf(s);
#pragma unroll
    for (int j = 0; j < 4; ++j) {
        v[j].x -= lse; v[j].y -= lse; v[j].z -= lse; v[j].w -= lse;
        *(float4*)(row + 4 * j) = v[j];
    }
}

extern "C" void kernel_launch(void* const* d_in, const int* in_sizes, int n_in,
                              void* d_out, int out_size, void* d_ws, size_t ws_size,
                              hipStream_t stream) {
    const float* x  = (const float*)d_in[0];
    const int*   ei = (const int*)d_in[1];
    const float* W1 = (const float*)d_in[2];
    const float* b1 = (const float*)d_in[3];
    const float* W2 = (const float*)d_in[4];
    const float* b2 = (const float*)d_in[5];
    float* out = (float*)d_out;

    const int n = N_NODES;
    const int e = E_EDGES;
    const int* srcp = ei;        // edge_index[0]
    const int* dstp = ei + e;    // edge_index[1]

    // workspace layout (floats)
    float* ws   = (float*)d_ws;
    float* dinv = ws;                       // n
    float* norm = dinv + n;                 // e
    float* h1   = norm + e;                 // n*HID
    float* out1 = h1 + (size_t)n * HID;     // n*HID
    float* h2   = out1 + (size_t)n * HID;   // n*OUT_DIM

    const int B = 256;
    auto blk = [](long long total, int b) { return (int)((total + b - 1) / b); };

    // degree + norm (shared by both layers)
    deg_init<<<blk(n, B), B, 0, stream>>>(dinv, n);
    deg_count<<<blk(e, B), B, 0, stream>>>(dstp, dinv, e);
    deg_rsqrt<<<blk(n, B), B, 0, stream>>>(dinv, n);
    edge_norm<<<blk(e, B), B, 0, stream>>>(srcp, dstp, dinv, norm, e);

    // layer 1
    gemm_kernel<IN_DIM, HID><<<blk((long long)n * HID, B), B, 0, stream>>>(x, W1, h1, n);
    agg_init<HID><<<blk((long long)n * HID, B), B, 0, stream>>>(h1, dinv, b1, out1, n);
    agg_edges<HID><<<blk((long long)e * HID, B), B, 0, stream>>>(srcp, dstp, norm, h1, out1, e);
    relu_kernel<<<blk((long long)n * HID, B), B, 0, stream>>>(out1, n * HID);

    // layer 2
    gemm_kernel<HID, OUT_DIM><<<blk((long long)n * OUT_DIM, B), B, 0, stream>>>(out1, W2, h2, n);
    agg_init<OUT_DIM><<<blk((long long)n * OUT_DIM, B), B, 0, stream>>>(h2, dinv, b2, out, n);
    agg_edges<OUT_DIM><<<blk((long long)e * OUT_DIM, B), B, 0, stream>>>(srcp, dstp, norm, h2, out, e);

    // log_softmax in place on d_out
    log_softmax16<<<blk(n, B), B, 0, stream>>>(out, n);
}

// Round 2
// 618.940 us; speedup vs baseline: 1.5275x; 1.5275x over previous
//
#include <hip/hip_runtime.h>
#include <hip/hip_bf16.h>

#define N_NODES 50000
#define E_EDGES 800000
#define IN_DIM  256
#define HID     128
#define OUT_DIM 16

using frag_ab = __attribute__((ext_vector_type(8))) short;  // 8 bf16
using frag_cd = __attribute__((ext_vector_type(4))) float;  // 4 fp32

static __device__ inline short f2bf(float f) {
    // round-to-nearest-even fp32 -> bf16
    union { float f; unsigned u; } v; v.f = f;
    unsigned r = (v.u + 0x7fffu + ((v.u >> 16) & 1u)) >> 16;
    return (short)r;
}

// ---------------- degree / norm precompute ----------------

__global__ void deg_init(float* __restrict__ deg, int n) {
    int i = blockIdx.x * blockDim.x + threadIdx.x;
    if (i < n) deg[i] = 1.0f;  // self loop contributes 1
}

__global__ void deg_count(const int* __restrict__ dst, float* __restrict__ deg, int e) {
    int i = blockIdx.x * blockDim.x + threadIdx.x;
    if (i < e) atomicAdd(&deg[dst[i]], 1.0f);
}

__global__ void deg_rsqrt(float* __restrict__ deg, int n) {
    int i = blockIdx.x * blockDim.x + threadIdx.x;
    if (i < n) deg[i] = rsqrtf(deg[i]);  // deg >= 1 always
}

__global__ void edge_norm(const int* __restrict__ src, const int* __restrict__ dst,
                          const float* __restrict__ dinv, float* __restrict__ norm, int e) {
    int i = blockIdx.x * blockDim.x + threadIdx.x;
    if (i < e) norm[i] = dinv[src[i]] * dinv[dst[i]];
}

// ---------------- W1 transpose + bf16 convert: Wt[c][k] = bf16(W[k][c]) ----
__global__ void w1_transpose(const float* __restrict__ W, short* __restrict__ wt) {
    int i = blockIdx.x * blockDim.x + threadIdx.x;
    if (i >= IN_DIM * HID) return;
    int k = i / HID, c = i % HID;
    wt[(size_t)c * IN_DIM + k] = f2bf(W[i]);
}

// ---------------- layer-1 GEMM via bf16 MFMA ----------------
// h[n,128] = x[n,256] @ W1[256,128]. Block = 4 waves; each wave computes a
// 16-row x 128-col strip (8 MFMA tiles along N, 8 K-steps of 32).
// A (x rows) converted fp32->bf16 on the fly; B from pre-transposed bf16 Wt.
// MFMA 16x16x32 layouts (guide §3):
//   A frag: lane holds A[m=lane&15][k=(lane>>4)*8 + j], j=0..7
//   B frag: lane holds B[k=(lane>>4)*8 + j][n=lane&15]
//   C/D:    col=lane&15, row=(lane>>4)*4 + reg
__global__ __launch_bounds__(256) void gemm1_mfma(const float* __restrict__ x,
                                                  const short* __restrict__ wt,
                                                  float* __restrict__ h) {
    int wave = threadIdx.x >> 6;
    int lane = threadIdx.x & 63;
    int m = lane & 15;      // A row / B col within tile
    int q = lane >> 4;      // quad -> k-offset selector
    int row0 = blockIdx.x * 64 + wave * 16;
    int arow_idx = row0 + m;
    const float* arow = x + (size_t)(arow_idx < N_NODES ? arow_idx : 0) * IN_DIM;

    frag_cd acc[8];
#pragma unroll
    for (int t = 0; t < 8; ++t) acc[t] = frag_cd{0.f, 0.f, 0.f, 0.f};

#pragma unroll
    for (int kt = 0; kt < 8; ++kt) {
        int k = kt * 32 + q * 8;
        float4 f0 = *(const float4*)(arow + k);
        float4 f1 = *(const float4*)(arow + k + 4);
        frag_ab a;
        a[0] = f2bf(f0.x); a[1] = f2bf(f0.y); a[2] = f2bf(f0.z); a[3] = f2bf(f0.w);
        a[4] = f2bf(f1.x); a[5] = f2bf(f1.y); a[6] = f2bf(f1.z); a[7] = f2bf(f1.w);
#pragma unroll
        for (int t = 0; t < 8; ++t) {
            frag_ab b = *(const frag_ab*)(wt + (size_t)(t * 16 + m) * IN_DIM + k);
            acc[t] = __builtin_amdgcn_mfma_f32_16x16x32_bf16(a, b, acc[t], 0, 0, 0);
        }
    }

#pragma unroll
    for (int t = 0; t < 8; ++t) {
#pragma unroll
        for (int r = 0; r < 4; ++r) {
            int orow = row0 + q * 4 + r;
            if (orow < N_NODES) h[(size_t)orow * HID + t * 16 + m] = acc[t][r];
        }
    }
}

// ---------------- layer-2 GEMM (fp32, small): thread = (node, 4 features) --
__global__ void gemm2_kernel(const float* __restrict__ h, const float* __restrict__ W,
                             float* __restrict__ out, int n) {
    int idx = blockIdx.x * blockDim.x + threadIdx.x;
    if (idx >= n * 4) return;
    int node = idx >> 2;
    int f4 = (idx & 3) << 2;
    const float* hr = h + (size_t)node * HID;
    float4 acc = {0.f, 0.f, 0.f, 0.f};
#pragma unroll 4
    for (int k = 0; k < HID; ++k) {
        float xv = hr[k];
        float4 wv = *(const float4*)(W + k * OUT_DIM + f4);
        acc.x += xv * wv.x; acc.y += xv * wv.y;
        acc.z += xv * wv.z; acc.w += xv * wv.w;
    }
    *(float4*)(out + (size_t)node * OUT_DIM + f4) = acc;
}

// ---------------- aggregation ----------------
template<int M>
__global__ void agg_init(const float* __restrict__ h, const float* __restrict__ dinv,
                         const float* __restrict__ b, float* __restrict__ out, int n) {
    int idx = blockIdx.x * blockDim.x + threadIdx.x;
    if (idx >= n * M) return;
    int node = idx / M;
    int f    = idx % M;
    float di = dinv[node];
    out[idx] = b[f] + h[idx] * di * di;
}

template<int M>
__global__ void agg_edges(const int* __restrict__ src, const int* __restrict__ dst,
                          const float* __restrict__ norm, const float* __restrict__ h,
                          float* __restrict__ out, int e) {
    int idx = blockIdx.x * blockDim.x + threadIdx.x;
    if (idx >= e * M) return;
    int ed = idx / M;
    int f  = idx % M;
    int s  = src[ed];
    int d  = dst[ed];
    float v = h[(size_t)s * M + f] * norm[ed];
    atomicAdd(&out[(size_t)d * M + f], v);
}

__global__ void relu_kernel(float* __restrict__ a, int total) {
    int i = blockIdx.x * blockDim.x + threadIdx.x;
    if (i < total) a[i] = fmaxf(a[i], 0.0f);
}

// ---------------- log_softmax over 16 features, in place ----------------
__global__ void log_softmax16(float* __restrict__ out, int n) {
    int i = blockIdx.x * blockDim.x + threadIdx.x;
    if (i >= n) return;
    float* row = out + (size_t)i * 16;
    float4 v[4];
#pragma unroll
    for (int j = 0; j < 4; ++j) v[j] = *(float4*)(row + 4 * j);
    float m = -1e30f;
#pragma unroll
    for (int j = 0; j < 4; ++j)
        m = fmaxf(m, fmaxf(fmaxf(v[j].x, v[j].y), fmaxf(v[j].z, v[j].w)));
    float s = 0.0f;
#pragma unroll
    for (int j = 0; j < 4; ++j)
        s += expf(v[j].x - m) + expf(v[j].y - m) + expf(v[j].z - m) + expf(v[j].w - m);
    float lse = m + logf(s);
#pragma unroll
    for (int j = 0; j < 4; ++j) {
        v[j].x -= lse; v[j].y -= lse; v[j].z -= lse; v[j].w -= lse;
        *(float4*)(row + 4 * j) = v[j];
    }
}

extern "C" void kernel_launch(void* const* d_in, const int* in_sizes, int n_in,
                              void* d_out, int out_size, void* d_ws, size_t ws_size,
                              hipStream_t stream) {
    const float* x  = (const float*)d_in[0];
    const int*   ei = (const int*)d_in[1];
    const float* W1 = (const float*)d_in[2];
    const float* b1 = (const float*)d_in[3];
    const float* W2 = (const float*)d_in[4];
    const float* b2 = (const float*)d_in[5];
    float* out = (float*)d_out;

    const int n = N_NODES;
    const int e = E_EDGES;
    const int* srcp = ei;        // edge_index[0]
    const int* dstp = ei + e;    // edge_index[1]

    // workspace layout (floats)
    float* ws   = (float*)d_ws;
    float* dinv = ws;                          // n
    float* norm = dinv + n;                    // e
    float* h1   = norm + e;                    // n*HID
    float* out1 = h1 + (size_t)n * HID;        // n*HID
    float* h2   = out1 + (size_t)n * HID;      // n*OUT_DIM
    short* w1t  = (short*)(h2 + (size_t)n * OUT_DIM);  // HID*IN_DIM bf16

    const int B = 256;
    auto blk = [](long long total, int b) { return (int)((total + b - 1) / b); };

    // degree + norm (shared by both layers)
    deg_init<<<blk(n, B), B, 0, stream>>>(dinv, n);
    deg_count<<<blk(e, B), B, 0, stream>>>(dstp, dinv, e);
    deg_rsqrt<<<blk(n, B), B, 0, stream>>>(dinv, n);
    edge_norm<<<blk(e, B), B, 0, stream>>>(srcp, dstp, dinv, norm, e);

    // layer 1: MFMA GEMM
    w1_transpose<<<blk(IN_DIM * HID, B), B, 0, stream>>>(W1, w1t);
    gemm1_mfma<<<blk((long long)n, 64), 256, 0, stream>>>(x, w1t, h1);
    agg_init<HID><<<blk((long long)n * HID, B), B, 0, stream>>>(h1, dinv, b1, out1, n);
    agg_edges<HID><<<blk((long long)e * HID, B), B, 0, stream>>>(srcp, dstp, norm, h1, out1, e);
    relu_kernel<<<blk((long long)n * HID, B), B, 0, stream>>>(out1, n * HID);

    // layer 2
    gemm2_kernel<<<blk((long long)n * 4, B), B, 0, stream>>>(out1, W2, h2, n);
    agg_init<OUT_DIM><<<blk((long long)n * OUT_DIM, B), B, 0, stream>>>(h2, dinv, b2, out, n);
    agg_edges<OUT_DIM><<<blk((long long)e * OUT_DIM, B), B, 0, stream>>>(srcp, dstp, norm, h2, out, e);

    // log_softmax in place on d_out
    log_softmax16<<<blk(n, B), B, 0, stream>>>(out, n);
}

// Round 3
// 504.093 us; speedup vs baseline: 1.8755x; 1.2278x over previous
//
#include <hip/hip_runtime.h>
#include <hip/hip_bf16.h>

#define N_NODES 50000
#define E_EDGES 800000
#define IN_DIM  256
#define HID     128
#define OUT_DIM 16

using frag_ab = __attribute__((ext_vector_type(8))) short;  // 8 bf16
using frag_cd = __attribute__((ext_vector_type(4))) float;  // 4 fp32

static __device__ inline short f2bf(float f) {
    union { float f; unsigned u; } v; v.f = f;
    unsigned r = (v.u + 0x7fffu + ((v.u >> 16) & 1u)) >> 16;
    return (short)r;
}
static __device__ inline float bf2f(short s) {
    union { unsigned u; float f; } v; v.u = ((unsigned)(unsigned short)s) << 16;
    return v.f;
}

// ---------------- CSR build (counting sort by dst) ----------------

__global__ void hist_kernel(const int* __restrict__ dst, int* __restrict__ cnt, int e) {
    int i = blockIdx.x * blockDim.x + threadIdx.x;
    if (i < e) atomicAdd(&cnt[dst[i]], 1);
}

__global__ void dinv_kernel(const int* __restrict__ cnt, float* __restrict__ dinv, int n) {
    int i = blockIdx.x * blockDim.x + threadIdx.x;
    if (i < n) dinv[i] = rsqrtf((float)(cnt[i] + 1));  // +1 self loop
}

#define SCAN_T 1024
__global__ __launch_bounds__(SCAN_T) void scan_kernel(const int* __restrict__ cnt,
                                                      int* __restrict__ rowptr,
                                                      int* __restrict__ cursor, int n) {
    __shared__ int sums[SCAN_T];
    int t = threadIdx.x;
    int per = (n + SCAN_T - 1) / SCAN_T;
    int lo = t * per, hi = min(lo + per, n);
    int s = 0;
    for (int i = lo; i < hi; ++i) s += cnt[i];
    sums[t] = s;
    __syncthreads();
    for (int off = 1; off < SCAN_T; off <<= 1) {
        int v = (t >= off) ? sums[t - off] : 0;
        __syncthreads();
        sums[t] += v;
        __syncthreads();
    }
    int run = (t > 0) ? sums[t - 1] : 0;
    for (int i = lo; i < hi; ++i) {
        rowptr[i] = run; cursor[i] = run;
        run += cnt[i];
    }
    if (t == SCAN_T - 1) rowptr[n] = run;
}

__global__ void scatter_kernel(const int* __restrict__ src, const int* __restrict__ dst,
                               int* __restrict__ cursor, int* __restrict__ ssrc, int e) {
    int i = blockIdx.x * blockDim.x + threadIdx.x;
    if (i < e) {
        int pos = atomicAdd(&cursor[dst[i]], 1);
        ssrc[pos] = src[i];
    }
}

// ---------------- W1 transpose + bf16 convert ----------------
__global__ void w1_transpose(const float* __restrict__ W, short* __restrict__ wt) {
    int i = blockIdx.x * blockDim.x + threadIdx.x;
    if (i >= IN_DIM * HID) return;
    int k = i / HID, c = i % HID;
    wt[(size_t)c * IN_DIM + k] = f2bf(W[i]);
}

// ---------------- layer-1 GEMM via bf16 MFMA, bf16 output ----------------
__global__ __launch_bounds__(256) void gemm1_mfma(const float* __restrict__ x,
                                                  const short* __restrict__ wt,
                                                  short* __restrict__ h) {
    int wave = threadIdx.x >> 6;
    int lane = threadIdx.x & 63;
    int m = lane & 15;
    int q = lane >> 4;
    int row0 = blockIdx.x * 64 + wave * 16;
    int arow_idx = row0 + m;
    const float* arow = x + (size_t)(arow_idx < N_NODES ? arow_idx : 0) * IN_DIM;

    frag_cd acc[8];
#pragma unroll
    for (int t = 0; t < 8; ++t) acc[t] = frag_cd{0.f, 0.f, 0.f, 0.f};

#pragma unroll
    for (int kt = 0; kt < 8; ++kt) {
        int k = kt * 32 + q * 8;
        float4 f0 = *(const float4*)(arow + k);
        float4 f1 = *(const float4*)(arow + k + 4);
        frag_ab a;
        a[0] = f2bf(f0.x); a[1] = f2bf(f0.y); a[2] = f2bf(f0.z); a[3] = f2bf(f0.w);
        a[4] = f2bf(f1.x); a[5] = f2bf(f1.y); a[6] = f2bf(f1.z); a[7] = f2bf(f1.w);
#pragma unroll
        for (int t = 0; t < 8; ++t) {
            frag_ab b = *(const frag_ab*)(wt + (size_t)(t * 16 + m) * IN_DIM + k);
            acc[t] = __builtin_amdgcn_mfma_f32_16x16x32_bf16(a, b, acc[t], 0, 0, 0);
        }
    }

#pragma unroll
    for (int t = 0; t < 8; ++t) {
#pragma unroll
        for (int r = 0; r < 4; ++r) {
            int orow = row0 + q * 4 + r;
            if (orow < N_NODES) h[(size_t)orow * HID + t * 16 + m] = f2bf(acc[t][r]);
        }
    }
}

// ---------------- layer-1 pull aggregation (+bias, self-loop, ReLU) -------
__global__ __launch_bounds__(256) void agg1_pull(const short* __restrict__ h1,
                                                 const float* __restrict__ dinv,
                                                 const float* __restrict__ b1,
                                                 const int* __restrict__ rowptr,
                                                 const int* __restrict__ ssrc,
                                                 float* __restrict__ out1) {
    int node = blockIdx.x * 2 + (threadIdx.x >> 7);
    int f = threadIdx.x & 127;
    if (node >= N_NODES) return;
    float dd = dinv[node];
    float acc = b1[f] + bf2f(h1[(size_t)node * HID + f]) * dd * dd;
    int lo = rowptr[node], hi = rowptr[node + 1];
    for (int e = lo; e < hi; ++e) {
        int s = ssrc[e];
        float w = dinv[s] * dd;
        acc += bf2f(h1[(size_t)s * HID + f]) * w;
    }
    out1[(size_t)node * HID + f] = fmaxf(acc, 0.0f);
}

// ---------------- layer-2 GEMM (fp32, small) ----------------
__global__ void gemm2_kernel(const float* __restrict__ h, const float* __restrict__ W,
                             float* __restrict__ out, int n) {
    int idx = blockIdx.x * blockDim.x + threadIdx.x;
    if (idx >= n * 4) return;
    int node = idx >> 2;
    int f4 = (idx & 3) << 2;
    const float* hr = h + (size_t)node * HID;
    float4 acc = {0.f, 0.f, 0.f, 0.f};
#pragma unroll 4
    for (int k = 0; k < HID; ++k) {
        float xv = hr[k];
        float4 wv = *(const float4*)(W + k * OUT_DIM + f4);
        acc.x += xv * wv.x; acc.y += xv * wv.y;
        acc.z += xv * wv.z; acc.w += xv * wv.w;
    }
    *(float4*)(out + (size_t)node * OUT_DIM + f4) = acc;
}

// ---------------- layer-2 pull aggregation + fused log_softmax ------------
__global__ __launch_bounds__(256) void agg2_pull(const float* __restrict__ h2,
                                                 const float* __restrict__ dinv,
                                                 const float* __restrict__ b2,
                                                 const int* __restrict__ rowptr,
                                                 const int* __restrict__ ssrc,
                                                 float* __restrict__ out) {
    int node = blockIdx.x * 16 + (threadIdx.x >> 4);
    int f = threadIdx.x & 15;
    if (node >= N_NODES) return;
    float dd = dinv[node];
    float acc = b2[f] + h2[(size_t)node * OUT_DIM + f] * dd * dd;
    int lo = rowptr[node], hi = rowptr[node + 1];
    for (int e = lo; e < hi; ++e) {
        int s = ssrc[e];
        acc += h2[(size_t)s * OUT_DIM + f] * (dinv[s] * dd);
    }
    // log_softmax across the 16 lanes of this node
    float m = acc;
#pragma unroll
    for (int msk = 1; msk < 16; msk <<= 1) m = fmaxf(m, __shfl_xor(m, msk, 16));
    float ex = __expf(acc - m);
    float ssum = ex;
#pragma unroll
    for (int msk = 1; msk < 16; msk <<= 1) ssum += __shfl_xor(ssum, msk, 16);
    out[(size_t)node * OUT_DIM + f] = acc - m - logf(ssum);
}

extern "C" void kernel_launch(void* const* d_in, const int* in_sizes, int n_in,
                              void* d_out, int out_size, void* d_ws, size_t ws_size,
                              hipStream_t stream) {
    const float* x  = (const float*)d_in[0];
    const int*   ei = (const int*)d_in[1];
    const float* W1 = (const float*)d_in[2];
    const float* b1 = (const float*)d_in[3];
    const float* W2 = (const float*)d_in[4];
    const float* b2 = (const float*)d_in[5];
    float* out = (float*)d_out;

    const int n = N_NODES;
    const int e = E_EDGES;
    const int* srcp = ei;        // edge_index[0]
    const int* dstp = ei + e;    // edge_index[1]

    // workspace layout
    char* w = (char*)d_ws;
    int*   cnt    = (int*)w;                 w += (size_t)n * 4;
    int*   rowptr = (int*)w;                 w += (size_t)(n + 1) * 4;
    int*   cursor = (int*)w;                 w += (size_t)n * 4;
    float* dinv   = (float*)w;               w += (size_t)n * 4;
    int*   ssrc   = (int*)w;                 w += (size_t)e * 4;
    short* w1t    = (short*)w;               w += (size_t)IN_DIM * HID * 2;
    short* h1     = (short*)w;               w += (size_t)n * HID * 2;   // bf16
    float* out1   = (float*)w;               w += (size_t)n * HID * 4;
    float* h2     = (float*)w;               w += (size_t)n * OUT_DIM * 4;

    const int B = 256;
    auto blk = [](long long total, int b) { return (int)((total + b - 1) / b); };

    // CSR build (shared by both layers)
    hipMemsetAsync(cnt, 0, (size_t)n * 4, stream);
    hist_kernel<<<blk(e, B), B, 0, stream>>>(dstp, cnt, e);
    dinv_kernel<<<blk(n, B), B, 0, stream>>>(cnt, dinv, n);
    scan_kernel<<<1, SCAN_T, 0, stream>>>(cnt, rowptr, cursor, n);
    scatter_kernel<<<blk(e, B), B, 0, stream>>>(srcp, dstp, cursor, ssrc, e);

    // layer 1
    w1_transpose<<<blk(IN_DIM * HID, B), B, 0, stream>>>(W1, w1t);
    gemm1_mfma<<<blk(n, 64), 256, 0, stream>>>(x, w1t, h1);
    agg1_pull<<<blk(n, 2), 256, 0, stream>>>(h1, dinv, b1, rowptr, ssrc, out1);

    // layer 2
    gemm2_kernel<<<blk((long long)n * 4, B), B, 0, stream>>>(out1, W2, h2, n);
    agg2_pull<<<blk(n, 16), 256, 0, stream>>>(h2, dinv, b2, rowptr, ssrc, out);
}

// Round 4
// 312.951 us; speedup vs baseline: 3.0210x; 1.6108x over previous
//
#include <hip/hip_runtime.h>
#include <hip/hip_bf16.h>

#define N_NODES 50000
#define E_EDGES 800000
#define IN_DIM  256
#define HID     128
#define OUT_DIM 16

using frag_ab = __attribute__((ext_vector_type(8))) short;  // 8 bf16
using frag_cd = __attribute__((ext_vector_type(4))) float;  // 4 fp32

static __device__ inline short f2bf(float f) {
    union { float f; unsigned u; } v; v.f = f;
    unsigned r = (v.u + 0x7fffu + ((v.u >> 16) & 1u)) >> 16;
    return (short)r;
}
static __device__ inline float bflo(unsigned u) {   // low bf16 of dword -> f32
    union { unsigned u; float f; } v; v.u = u << 16; return v.f;
}
static __device__ inline float bfhi(unsigned u) {   // high bf16 of dword -> f32
    union { unsigned u; float f; } v; v.u = u & 0xffff0000u; return v.f;
}

// ---------------- CSR build (counting sort by dst) ----------------

__global__ void hist_kernel(const int* __restrict__ dst, int* __restrict__ cnt, int e) {
    int i = blockIdx.x * blockDim.x + threadIdx.x;
    if (i < e) atomicAdd(&cnt[dst[i]], 1);
}

__global__ void dinv_kernel(const int* __restrict__ cnt, float* __restrict__ dinv, int n) {
    int i = blockIdx.x * blockDim.x + threadIdx.x;
    if (i < n) dinv[i] = rsqrtf((float)(cnt[i] + 1));  // +1 self loop
}

// 3-phase exclusive scan of cnt[n] -> rowptr/cursor
#define SB 256
__global__ __launch_bounds__(SB) void scan1(const int* __restrict__ cnt,
                                            int* __restrict__ part,
                                            int* __restrict__ btot, int n) {
    __shared__ int sm[SB];
    int t = threadIdx.x, i = blockIdx.x * SB + t;
    int v = (i < n) ? cnt[i] : 0;
    sm[t] = v;
    __syncthreads();
    for (int off = 1; off < SB; off <<= 1) {
        int u = (t >= off) ? sm[t - off] : 0;
        __syncthreads();
        sm[t] += u;
        __syncthreads();
    }
    if (i < n) part[i] = sm[t] - v;          // block-local exclusive
    if (t == SB - 1) btot[blockIdx.x] = sm[t];
}

__global__ __launch_bounds__(SB) void scan2(int* __restrict__ btot, int nb) {
    __shared__ int sm[SB];
    int t = threadIdx.x;
    int v = (t < nb) ? btot[t] : 0;
    sm[t] = v;
    __syncthreads();
    for (int off = 1; off < SB; off <<= 1) {
        int u = (t >= off) ? sm[t - off] : 0;
        __syncthreads();
        sm[t] += u;
        __syncthreads();
    }
    if (t < nb) btot[t] = sm[t] - v;         // exclusive block offsets
}

__global__ void scan3(const int* __restrict__ part, const int* __restrict__ btot,
                      int* __restrict__ rowptr, int* __restrict__ cursor, int n) {
    int i = blockIdx.x * blockDim.x + threadIdx.x;
    if (i < n) {
        int v = part[i] + btot[i >> 8];
        rowptr[i] = v;
        cursor[i] = v;
    } else if (i == n) {
        rowptr[n] = E_EDGES;
    }
}

__global__ void scatter_kernel(const int* __restrict__ src, const int* __restrict__ dst,
                               int* __restrict__ cursor, int* __restrict__ ssrc, int e) {
    int i = blockIdx.x * blockDim.x + threadIdx.x;
    if (i < e) {
        int pos = atomicAdd(&cursor[dst[i]], 1);
        ssrc[pos] = src[i];
    }
}

// ---------------- W1 transpose + bf16 convert ----------------
__global__ void w1_transpose(const float* __restrict__ W, short* __restrict__ wt) {
    int i = blockIdx.x * blockDim.x + threadIdx.x;
    if (i >= IN_DIM * HID) return;
    int k = i / HID, c = i % HID;
    wt[(size_t)c * IN_DIM + k] = f2bf(W[i]);
}

// ---------------- layer-1 GEMM via bf16 MFMA; writes h1s = (x@W1)*dinv ----
__global__ __launch_bounds__(256) void gemm1_mfma(const float* __restrict__ x,
                                                  const short* __restrict__ wt,
                                                  const float* __restrict__ dinv,
                                                  short* __restrict__ h) {
    int wave = threadIdx.x >> 6;
    int lane = threadIdx.x & 63;
    int m = lane & 15;
    int q = lane >> 4;
    int row0 = blockIdx.x * 64 + wave * 16;
    int arow_idx = row0 + m;
    const float* arow = x + (size_t)(arow_idx < N_NODES ? arow_idx : 0) * IN_DIM;

    frag_cd acc[8];
#pragma unroll
    for (int t = 0; t < 8; ++t) acc[t] = frag_cd{0.f, 0.f, 0.f, 0.f};

#pragma unroll
    for (int kt = 0; kt < 8; ++kt) {
        int k = kt * 32 + q * 8;
        float4 f0 = *(const float4*)(arow + k);
        float4 f1 = *(const float4*)(arow + k + 4);
        frag_ab a;
        a[0] = f2bf(f0.x); a[1] = f2bf(f0.y); a[2] = f2bf(f0.z); a[3] = f2bf(f0.w);
        a[4] = f2bf(f1.x); a[5] = f2bf(f1.y); a[6] = f2bf(f1.z); a[7] = f2bf(f1.w);
#pragma unroll
        for (int t = 0; t < 8; ++t) {
            frag_ab b = *(const frag_ab*)(wt + (size_t)(t * 16 + m) * IN_DIM + k);
            acc[t] = __builtin_amdgcn_mfma_f32_16x16x32_bf16(a, b, acc[t], 0, 0, 0);
        }
    }

    float dv[4];
#pragma unroll
    for (int r = 0; r < 4; ++r) {
        int orow = row0 + q * 4 + r;
        dv[r] = (orow < N_NODES) ? dinv[orow] : 0.f;
    }
#pragma unroll
    for (int t = 0; t < 8; ++t) {
#pragma unroll
        for (int r = 0; r < 4; ++r) {
            int orow = row0 + q * 4 + r;
            if (orow < N_NODES)
                h[(size_t)orow * HID + t * 16 + m] = f2bf(acc[t][r] * dv[r]);
        }
    }
}

// ---------------- layer-1 pull: one node per wave, 2 edges/iter -----------
// lane = eo*32 + g; eo picks edge in pair, g picks 4 bf16 features (dwordx2).
// out1 = relu(b1 + dd * (h1s[node] + sum_s h1s[s]))
__global__ __launch_bounds__(256) void agg1_pull(const short* __restrict__ h1s,
                                                 const float* __restrict__ dinv,
                                                 const float* __restrict__ b1,
                                                 const int* __restrict__ rowptr,
                                                 const int* __restrict__ ssrc,
                                                 float* __restrict__ out1) {
    int wave = threadIdx.x >> 6;
    int lane = threadIdx.x & 63;
    int node = __builtin_amdgcn_readfirstlane(blockIdx.x * 4 + wave);
    if (node >= N_NODES) return;
    int eo = lane >> 5;       // 0/1: which edge of the pair
    int g  = lane & 31;       // feature quad: features 4g..4g+3

    int lo = rowptr[node], hi = rowptr[node + 1];
    float a0 = 0.f, a1 = 0.f, a2 = 0.f, a3 = 0.f;

    if (eo == 0) {            // self-loop row (dd factor applied at the end)
        uint2 u = *(const uint2*)(h1s + (size_t)node * HID + g * 4);
        a0 = bflo(u.x); a1 = bfhi(u.x); a2 = bflo(u.y); a3 = bfhi(u.y);
    }

    int e = lo;
#pragma unroll 2
    for (; e + 2 <= hi; e += 2) {
        int s0 = ssrc[e];
        int s1 = ssrc[e + 1];
        int s = eo ? s1 : s0;
        uint2 u = *(const uint2*)(h1s + (size_t)s * HID + g * 4);
        a0 += bflo(u.x); a1 += bfhi(u.x); a2 += bflo(u.y); a3 += bfhi(u.y);
    }
    if (e < hi && eo == 0) {  // odd leftover edge
        int s = ssrc[e];
        uint2 u = *(const uint2*)(h1s + (size_t)s * HID + g * 4);
        a0 += bflo(u.x); a1 += bfhi(u.x); a2 += bflo(u.y); a3 += bfhi(u.y);
    }

    // combine the two edge-halves
    a0 += __shfl_xor(a0, 32);
    a1 += __shfl_xor(a1, 32);
    a2 += __shfl_xor(a2, 32);
    a3 += __shfl_xor(a3, 32);

    if (eo == 0) {
        float dd = dinv[node];
        float4 b = *(const float4*)(b1 + g * 4);
        float4 o;
        o.x = fmaxf(fmaf(dd, a0, b.x), 0.f);
        o.y = fmaxf(fmaf(dd, a1, b.y), 0.f);
        o.z = fmaxf(fmaf(dd, a2, b.z), 0.f);
        o.w = fmaxf(fmaf(dd, a3, b.w), 0.f);
        *(float4*)(out1 + (size_t)node * HID + g * 4) = o;
    }
}

// ---------------- layer-2 GEMM (fp32, small); writes h2s = (out1@W2)*dinv --
__global__ void gemm2_kernel(const float* __restrict__ h, const float* __restrict__ W,
                             const float* __restrict__ dinv, float* __restrict__ out, int n) {
    int idx = blockIdx.x * blockDim.x + threadIdx.x;
    if (idx >= n * 4) return;
    int node = idx >> 2;
    int f4 = (idx & 3) << 2;
    const float* hr = h + (size_t)node * HID;
    float4 acc = {0.f, 0.f, 0.f, 0.f};
#pragma unroll 4
    for (int k = 0; k < HID; ++k) {
        float xv = hr[k];
        float4 wv = *(const float4*)(W + k * OUT_DIM + f4);
        acc.x += xv * wv.x; acc.y += xv * wv.y;
        acc.z += xv * wv.z; acc.w += xv * wv.w;
    }
    float dv = dinv[node];
    acc.x *= dv; acc.y *= dv; acc.z *= dv; acc.w *= dv;
    *(float4*)(out + (size_t)node * OUT_DIM + f4) = acc;
}

// ---------------- layer-2 pull: one node per wave, 4 edges/iter,
// fused bias + log_softmax ----------------
__global__ __launch_bounds__(256) void agg2_pull(const float* __restrict__ h2s,
                                                 const float* __restrict__ dinv,
                                                 const float* __restrict__ b2,
                                                 const int* __restrict__ rowptr,
                                                 const int* __restrict__ ssrc,
                                                 float* __restrict__ out) {
    int wave = threadIdx.x >> 6;
    int lane = threadIdx.x & 63;
    int node = __builtin_amdgcn_readfirstlane(blockIdx.x * 4 + wave);
    if (node >= N_NODES) return;
    int eo = lane >> 4;       // 0..3: edge within quad
    int f  = lane & 15;       // feature

    int lo = rowptr[node], hi = rowptr[node + 1];
    float acc = (eo == 0) ? h2s[(size_t)node * OUT_DIM + f] : 0.f;

    int e = lo;
#pragma unroll 2
    for (; e + 4 <= hi; e += 4)
        acc += h2s[(size_t)ssrc[e + eo] * OUT_DIM + f];
    if (e + eo < hi)
        acc += h2s[(size_t)ssrc[e + eo] * OUT_DIM + f];

    acc += __shfl_xor(acc, 16);
    acc += __shfl_xor(acc, 32);

    float dd = dinv[node];
    float v = fmaf(dd, acc, b2[f]);

    // log_softmax across the 16 features (each 16-lane group identical)
    float m = v;
#pragma unroll
    for (int msk = 1; msk < 16; msk <<= 1) m = fmaxf(m, __shfl_xor(m, msk));
    float ex = __expf(v - m);
    float ssum = ex;
#pragma unroll
    for (int msk = 1; msk < 16; msk <<= 1) ssum += __shfl_xor(ssum, msk);
    if (eo == 0) out[(size_t)node * OUT_DIM + f] = v - m - __logf(ssum);
}

extern "C" void kernel_launch(void* const* d_in, const int* in_sizes, int n_in,
                              void* d_out, int out_size, void* d_ws, size_t ws_size,
                              hipStream_t stream) {
    const float* x  = (const float*)d_in[0];
    const int*   ei = (const int*)d_in[1];
    const float* W1 = (const float*)d_in[2];
    const float* b1 = (const float*)d_in[3];
    const float* W2 = (const float*)d_in[4];
    const float* b2 = (const float*)d_in[5];
    float* out = (float*)d_out;

    const int n = N_NODES;
    const int e = E_EDGES;
    const int* srcp = ei;        // edge_index[0]
    const int* dstp = ei + e;    // edge_index[1]

    // workspace layout
    char* w = (char*)d_ws;
    int*   cnt    = (int*)w;                 w += (size_t)n * 4;
    int*   part   = (int*)w;                 w += (size_t)n * 4;
    int*   btot   = (int*)w;                 w += (size_t)SB * 4;
    int*   rowptr = (int*)w;                 w += (size_t)(n + 1) * 4;
    int*   cursor = (int*)w;                 w += (size_t)n * 4;
    float* dinv   = (float*)w;               w += (size_t)n * 4;
    int*   ssrc   = (int*)w;                 w += (size_t)e * 4;
    short* w1t    = (short*)w;               w += (size_t)IN_DIM * HID * 2;
    short* h1s    = (short*)w;               w += (size_t)n * HID * 2;   // bf16, pre-scaled
    float* out1   = (float*)w;               w += (size_t)n * HID * 4;
    float* h2s    = (float*)w;               w += (size_t)n * OUT_DIM * 4;

    const int B = 256;
    auto blk = [](long long total, int b) { return (int)((total + b - 1) / b); };
    int nb = blk(n, SB);   // 196 scan blocks (<= SB so scan2 fits one block)

    // CSR build + degrees
    hipMemsetAsync(cnt, 0, (size_t)n * 4, stream);
    hist_kernel<<<blk(e, B), B, 0, stream>>>(dstp, cnt, e);
    dinv_kernel<<<blk(n, B), B, 0, stream>>>(cnt, dinv, n);
    scan1<<<nb, SB, 0, stream>>>(cnt, part, btot, n);
    scan2<<<1, SB, 0, stream>>>(btot, nb);
    scan3<<<blk(n + 1, B), B, 0, stream>>>(part, btot, rowptr, cursor, n);
    scatter_kernel<<<blk(e, B), B, 0, stream>>>(srcp, dstp, cursor, ssrc, e);

    // layer 1
    w1_transpose<<<blk(IN_DIM * HID, B), B, 0, stream>>>(W1, w1t);
    gemm1_mfma<<<blk(n, 64), 256, 0, stream>>>(x, w1t, dinv, h1s);
    agg1_pull<<<blk(n, 4), 256, 0, stream>>>(h1s, dinv, b1, rowptr, ssrc, out1);

    // layer 2
    gemm2_kernel<<<blk((long long)n * 4, B), B, 0, stream>>>(out1, W2, dinv, h2s, n);
    agg2_pull<<<blk(n, 4), 256, 0, stream>>>(h2s, dinv, b2, rowptr, ssrc, out);
}

// Round 5
// 244.215 us; speedup vs baseline: 3.8712x; 1.2815x over previous
//
#include <hip/hip_runtime.h>
#include <hip/hip_bf16.h>

#define N_NODES 50000
#define E_EDGES 800000
#define IN_DIM  256
#define HID     128
#define OUT_DIM 16

#define NBUCK 391    // ceil(50000/128) buckets of 128 nodes (dst>>7)
#define NBLK  128    // blocks for bucket phases A/C
#define P2CAP 4096   // max edges per bucket (mean 2046, sigma ~45)

using frag_ab = __attribute__((ext_vector_type(8))) short;  // 8 bf16
using frag_cd = __attribute__((ext_vector_type(4))) float;  // 4 fp32

static __device__ inline short f2bf(float f) {
    union { float f; unsigned u; } v; v.f = f;
    unsigned r = (v.u + 0x7fffu + ((v.u >> 16) & 1u)) >> 16;
    return (short)r;
}
static __device__ inline float bflo(unsigned u) {
    union { unsigned u; float f; } v; v.u = u << 16; return v.f;
}
static __device__ inline float bfhi(unsigned u) {
    union { unsigned u; float f; } v; v.u = u & 0xffff0000u; return v.f;
}
static __device__ inline unsigned packbf(float a, float b) {
    return (unsigned)(unsigned short)f2bf(a) | ((unsigned)(unsigned short)f2bf(b) << 16);
}

// ================= CSR build: 2-level bucketed counting sort =================

// Phase A: per-block per-bucket histogram (LDS), no global atomics.
__global__ __launch_bounds__(256) void csr_a(const int* __restrict__ dst,
                                             int* __restrict__ cnt_bb) {
    __shared__ int h[NBUCK];
    int t = threadIdx.x;
    for (int i = t; i < NBUCK; i += 256) h[i] = 0;
    __syncthreads();
    for (int i = blockIdx.x * 256 + t; i < E_EDGES; i += NBLK * 256)
        atomicAdd(&h[dst[i] >> 7], 1);
    __syncthreads();
    for (int i = t; i < NBUCK; i += 256) cnt_bb[i * NBLK + blockIdx.x] = h[i];
}

// Phase B1: per-bucket exclusive scan over the NBLK block counts + bucket total.
__global__ __launch_bounds__(NBLK) void csr_b1(int* __restrict__ cnt_bb,
                                               int* __restrict__ btot) {
    __shared__ int sm[NBLK];
    int b = blockIdx.x, t = threadIdx.x;
    int v = cnt_bb[b * NBLK + t];
    sm[t] = v;
    __syncthreads();
    for (int o = 1; o < NBLK; o <<= 1) {
        int u = (t >= o) ? sm[t - o] : 0;
        __syncthreads();
        sm[t] += u;
        __syncthreads();
    }
    cnt_bb[b * NBLK + t] = sm[t] - v;   // exclusive within bucket
    if (t == NBLK - 1) btot[b] = sm[t];
}

// Phase B2: exclusive scan of bucket totals -> bucket bases (single block).
__global__ __launch_bounds__(512) void csr_b2(const int* __restrict__ btot,
                                              int* __restrict__ bbase) {
    __shared__ int sm[512];
    int t = threadIdx.x;
    int v = (t < NBUCK) ? btot[t] : 0;
    sm[t] = v;
    __syncthreads();
    for (int o = 1; o < 512; o <<= 1) {
        int u = (t >= o) ? sm[t - o] : 0;
        __syncthreads();
        sm[t] += u;
        __syncthreads();
    }
    if (t < NBUCK) bbase[t] = sm[t] - v;
    if (t == 511) bbase[NBUCK] = sm[511];   // == E_EDGES
}

// Phase C: place packed (src | dstlow<<17) into per-(bucket,block) private
// contiguous sub-ranges -> write-combined lines.
__global__ __launch_bounds__(256) void csr_c(const int* __restrict__ src,
                                             const int* __restrict__ dst,
                                             const int* __restrict__ cnt_bb,
                                             const int* __restrict__ bbase,
                                             unsigned* __restrict__ tmp) {
    __shared__ int run[NBUCK];
    int t = threadIdx.x;
    for (int i = t; i < NBUCK; i += 256)
        run[i] = bbase[i] + cnt_bb[i * NBLK + blockIdx.x];
    __syncthreads();
    for (int i = blockIdx.x * 256 + t; i < E_EDGES; i += NBLK * 256) {
        int d = dst[i];
        int b = d >> 7;
        int pos = atomicAdd(&run[b], 1);
        tmp[pos] = (unsigned)src[i] | ((unsigned)(d & 127) << 17);
    }
}

// Pass 2: per-bucket in-LDS counting sort -> rowptr, dinv, ssrc (contiguous writes).
__global__ __launch_bounds__(256) void csr_p2(const unsigned* __restrict__ tmp,
                                              const int* __restrict__ bbase,
                                              int* __restrict__ rowptr,
                                              float* __restrict__ dinv,
                                              int* __restrict__ ssrc) {
    __shared__ unsigned ed[P2CAP];
    __shared__ int cnt[128];
    __shared__ int off[128];
    int b = blockIdx.x, t = threadIdx.x;
    int base = bbase[b];
    int m = bbase[b + 1] - base;
    if (m > P2CAP) m = P2CAP;   // statistically impossible; crash guard
    if (t < 128) cnt[t] = 0;
    __syncthreads();
    for (int i = t; i < m; i += 256) {
        unsigned v = tmp[base + i];
        ed[i] = v;
        atomicAdd(&cnt[v >> 17], 1);
    }
    __syncthreads();
    if (t < 128) off[t] = cnt[t];
    __syncthreads();
    for (int o = 1; o < 128; o <<= 1) {
        int u = (t >= o && t < 128) ? off[t - o] : 0;
        __syncthreads();
        if (t < 128) off[t] += u;
        __syncthreads();
    }
    if (t < 128) {
        int node = b * 128 + t;
        int ex = off[t] - cnt[t];   // exclusive
        if (node < N_NODES) {
            rowptr[node] = base + ex;
            dinv[node] = rsqrtf((float)(cnt[t] + 1));
        }
        off[t] = ex;   // running cursor
    }
    if (b == NBUCK - 1 && t == 0) rowptr[N_NODES] = E_EDGES;
    __syncthreads();
    for (int i = t; i < m; i += 256) {
        unsigned v = ed[i];
        int p = atomicAdd(&off[v >> 17], 1);
        ssrc[base + p] = (int)(v & 0x1FFFF);
    }
}

// ================= W1 transpose + bf16 convert =================
__global__ void w1_transpose(const float* __restrict__ W, short* __restrict__ wt) {
    int i = blockIdx.x * blockDim.x + threadIdx.x;
    if (i >= IN_DIM * HID) return;
    int k = i / HID, c = i % HID;
    wt[(size_t)c * IN_DIM + k] = f2bf(W[i]);
}

// ================= layer-1 GEMM via bf16 MFMA; h1s = (x@W1)*dinv ============
// All x loads + A-frag converts hoisted up front for MLP; B loads pipelined.
__global__ __launch_bounds__(256) void gemm1_mfma(const float* __restrict__ x,
                                                  const short* __restrict__ wt,
                                                  const float* __restrict__ dinv,
                                                  short* __restrict__ h) {
    int wave = threadIdx.x >> 6;
    int lane = threadIdx.x & 63;
    int m = lane & 15;
    int q = lane >> 4;
    int row0 = blockIdx.x * 64 + wave * 16;
    int arow_idx = row0 + m;
    const float4* arow4 = (const float4*)(x + (size_t)(arow_idx < N_NODES ? arow_idx : 0) * IN_DIM);

    float4 xr[16];
#pragma unroll
    for (int kt = 0; kt < 8; ++kt) {
        xr[2 * kt]     = arow4[kt * 8 + q * 2];
        xr[2 * kt + 1] = arow4[kt * 8 + q * 2 + 1];
    }
    frag_ab a[8];
#pragma unroll
    for (int kt = 0; kt < 8; ++kt) {
        float4 f0 = xr[2 * kt], f1 = xr[2 * kt + 1];
        a[kt][0] = f2bf(f0.x); a[kt][1] = f2bf(f0.y); a[kt][2] = f2bf(f0.z); a[kt][3] = f2bf(f0.w);
        a[kt][4] = f2bf(f1.x); a[kt][5] = f2bf(f1.y); a[kt][6] = f2bf(f1.z); a[kt][7] = f2bf(f1.w);
    }

    frag_cd acc[8];
#pragma unroll
    for (int t = 0; t < 8; ++t) acc[t] = frag_cd{0.f, 0.f, 0.f, 0.f};

#pragma unroll
    for (int kt = 0; kt < 8; ++kt) {
        int k = kt * 32 + q * 8;
#pragma unroll
        for (int t = 0; t < 8; ++t) {
            frag_ab b = *(const frag_ab*)(wt + (size_t)(t * 16 + m) * IN_DIM + k);
            acc[t] = __builtin_amdgcn_mfma_f32_16x16x32_bf16(a[kt], b, acc[t], 0, 0, 0);
        }
    }

    float dv[4];
#pragma unroll
    for (int r = 0; r < 4; ++r) {
        int orow = row0 + q * 4 + r;
        dv[r] = (orow < N_NODES) ? dinv[orow] : 0.f;
    }
#pragma unroll
    for (int t = 0; t < 8; ++t) {
#pragma unroll
        for (int r = 0; r < 4; ++r) {
            int orow = row0 + q * 4 + r;
            if (orow < N_NODES)
                h[(size_t)orow * HID + t * 16 + m] = f2bf(acc[t][r] * dv[r]);
        }
    }
}

// ================= layer-1 pull (node/wave, 2 edges/iter), bf16 out =========
__global__ __launch_bounds__(256) void agg1_pull(const short* __restrict__ h1s,
                                                 const float* __restrict__ dinv,
                                                 const float* __restrict__ b1,
                                                 const int* __restrict__ rowptr,
                                                 const int* __restrict__ ssrc,
                                                 unsigned* __restrict__ out1) {
    int wave = threadIdx.x >> 6;
    int lane = threadIdx.x & 63;
    int node = __builtin_amdgcn_readfirstlane(blockIdx.x * 4 + wave);
    if (node >= N_NODES) return;
    int eo = lane >> 5;
    int g  = lane & 31;

    int lo = rowptr[node], hi = rowptr[node + 1];
    float a0 = 0.f, a1 = 0.f, a2 = 0.f, a3 = 0.f;

    if (eo == 0) {
        uint2 u = *(const uint2*)(h1s + (size_t)node * HID + g * 4);
        a0 = bflo(u.x); a1 = bfhi(u.x); a2 = bflo(u.y); a3 = bfhi(u.y);
    }

    int e = lo;
#pragma unroll 2
    for (; e + 2 <= hi; e += 2) {
        int s0 = ssrc[e];
        int s1 = ssrc[e + 1];
        int s = eo ? s1 : s0;
        uint2 u = *(const uint2*)(h1s + (size_t)s * HID + g * 4);
        a0 += bflo(u.x); a1 += bfhi(u.x); a2 += bflo(u.y); a3 += bfhi(u.y);
    }
    if (e < hi && eo == 0) {
        int s = ssrc[e];
        uint2 u = *(const uint2*)(h1s + (size_t)s * HID + g * 4);
        a0 += bflo(u.x); a1 += bfhi(u.x); a2 += bflo(u.y); a3 += bfhi(u.y);
    }

    a0 += __shfl_xor(a0, 32);
    a1 += __shfl_xor(a1, 32);
    a2 += __shfl_xor(a2, 32);
    a3 += __shfl_xor(a3, 32);

    if (eo == 0) {
        float dd = dinv[node];
        float4 b = *(const float4*)(b1 + g * 4);
        float o0 = fmaxf(fmaf(dd, a0, b.x), 0.f);
        float o1 = fmaxf(fmaf(dd, a1, b.y), 0.f);
        float o2 = fmaxf(fmaf(dd, a2, b.z), 0.f);
        float o3 = fmaxf(fmaf(dd, a3, b.w), 0.f);
        uint2 st; st.x = packbf(o0, o1); st.y = packbf(o2, o3);
        *(uint2*)(out1 + (size_t)node * (HID / 2) + g * 2) = st;
    }
}

// ================= layer-2 GEMM (bf16 in, fp32 out); h2s = (out1@W2)*dinv ===
__global__ void gemm2_kernel(const unsigned* __restrict__ h, const float* __restrict__ W,
                             const float* __restrict__ dinv, float* __restrict__ out, int n) {
    int idx = blockIdx.x * blockDim.x + threadIdx.x;
    if (idx >= n * 4) return;
    int node = idx >> 2;
    int f4 = (idx & 3) << 2;
    const uint2* hr = (const uint2*)(h + (size_t)node * (HID / 2));
    float4 acc = {0.f, 0.f, 0.f, 0.f};
#pragma unroll 8
    for (int k = 0; k < HID; k += 4) {
        uint2 u = hr[k >> 2];
        float x0 = bflo(u.x), x1 = bfhi(u.x), x2 = bflo(u.y), x3 = bfhi(u.y);
        float4 w0 = *(const float4*)(W + (k + 0) * OUT_DIM + f4);
        float4 w1 = *(const float4*)(W + (k + 1) * OUT_DIM + f4);
        float4 w2 = *(const float4*)(W + (k + 2) * OUT_DIM + f4);
        float4 w3 = *(const float4*)(W + (k + 3) * OUT_DIM + f4);
        acc.x += x0 * w0.x + x1 * w1.x + x2 * w2.x + x3 * w3.x;
        acc.y += x0 * w0.y + x1 * w1.y + x2 * w2.y + x3 * w3.y;
        acc.z += x0 * w0.z + x1 * w1.z + x2 * w2.z + x3 * w3.z;
        acc.w += x0 * w0.w + x1 * w1.w + x2 * w2.w + x3 * w3.w;
    }
    float dv = dinv[node];
    acc.x *= dv; acc.y *= dv; acc.z *= dv; acc.w *= dv;
    *(float4*)(out + (size_t)node * OUT_DIM + f4) = acc;
}

// ================= layer-2 pull + fused bias + log_softmax =================
__global__ __launch_bounds__(256) void agg2_pull(const float* __restrict__ h2s,
                                                 const float* __restrict__ dinv,
                                                 const float* __restrict__ b2,
                                                 const int* __restrict__ rowptr,
                                                 const int* __restrict__ ssrc,
                                                 float* __restrict__ out) {
    int wave = threadIdx.x >> 6;
    int lane = threadIdx.x & 63;
    int node = __builtin_amdgcn_readfirstlane(blockIdx.x * 4 + wave);
    if (node >= N_NODES) return;
    int eo = lane >> 4;
    int f  = lane & 15;

    int lo = rowptr[node], hi = rowptr[node + 1];
    float acc = (eo == 0) ? h2s[(size_t)node * OUT_DIM + f] : 0.f;

    int e = lo;
#pragma unroll 2
    for (; e + 4 <= hi; e += 4)
        acc += h2s[(size_t)ssrc[e + eo] * OUT_DIM + f];
    if (e + eo < hi)
        acc += h2s[(size_t)ssrc[e + eo] * OUT_DIM + f];

    acc += __shfl_xor(acc, 16);
    acc += __shfl_xor(acc, 32);

    float dd = dinv[node];
    float v = fmaf(dd, acc, b2[f]);

    float m = v;
#pragma unroll
    for (int msk = 1; msk < 16; msk <<= 1) m = fmaxf(m, __shfl_xor(m, msk));
    float ex = __expf(v - m);
    float ssum = ex;
#pragma unroll
    for (int msk = 1; msk < 16; msk <<= 1) ssum += __shfl_xor(ssum, msk);
    if (eo == 0) out[(size_t)node * OUT_DIM + f] = v - m - __logf(ssum);
}

extern "C" void kernel_launch(void* const* d_in, const int* in_sizes, int n_in,
                              void* d_out, int out_size, void* d_ws, size_t ws_size,
                              hipStream_t stream) {
    const float* x  = (const float*)d_in[0];
    const int*   ei = (const int*)d_in[1];
    const float* W1 = (const float*)d_in[2];
    const float* b1 = (const float*)d_in[3];
    const float* W2 = (const float*)d_in[4];
    const float* b2 = (const float*)d_in[5];
    float* out = (float*)d_out;

    const int n = N_NODES;
    const int e = E_EDGES;
    const int* srcp = ei;        // edge_index[0]
    const int* dstp = ei + e;    // edge_index[1]

    // workspace layout
    char* w = (char*)d_ws;
    int*      cnt_bb = (int*)w;        w += (size_t)NBUCK * NBLK * 4;
    int*      btot   = (int*)w;        w += (size_t)NBUCK * 4;
    int*      bbase  = (int*)w;        w += (size_t)(NBUCK + 1) * 4;
    int*      rowptr = (int*)w;        w += (size_t)(n + 1) * 4;
    float*    dinv   = (float*)w;      w += (size_t)n * 4;
    unsigned* tmp    = (unsigned*)w;   w += (size_t)e * 4;
    int*      ssrc   = (int*)w;        w += (size_t)e * 4;
    short*    w1t    = (short*)w;      w += (size_t)IN_DIM * HID * 2;
    short*    h1s    = (short*)w;      w += (size_t)n * HID * 2;   // bf16, pre-scaled
    unsigned* out1   = (unsigned*)w;   w += (size_t)n * HID * 2;   // bf16 packed
    float*    h2s    = (float*)w;      w += (size_t)n * OUT_DIM * 4;

    const int B = 256;
    auto blk = [](long long total, int b) { return (int)((total + b - 1) / b); };

    // CSR build (bucketed counting sort; also produces rowptr + dinv)
    csr_a<<<NBLK, 256, 0, stream>>>(dstp, cnt_bb);
    csr_b1<<<NBUCK, NBLK, 0, stream>>>(cnt_bb, btot);
    csr_b2<<<1, 512, 0, stream>>>(btot, bbase);
    csr_c<<<NBLK, 256, 0, stream>>>(srcp, dstp, cnt_bb, bbase, tmp);
    csr_p2<<<NBUCK, 256, 0, stream>>>(tmp, bbase, rowptr, dinv, ssrc);

    // layer 1
    w1_transpose<<<blk(IN_DIM * HID, B), B, 0, stream>>>(W1, w1t);
    gemm1_mfma<<<blk(n, 64), 256, 0, stream>>>(x, w1t, dinv, h1s);
    agg1_pull<<<blk(n, 4), 256, 0, stream>>>(h1s, dinv, b1, rowptr, ssrc, out1);

    // layer 2
    gemm2_kernel<<<blk((long long)n * 4, B), B, 0, stream>>>(out1, W2, dinv, h2s, n);
    agg2_pull<<<blk(n, 4), 256, 0, stream>>>(h2s, dinv, b2, rowptr, ssrc, out);
}

// Round 6
// 218.534 us; speedup vs baseline: 4.3262x; 1.1175x over previous
//
#include <hip/hip_runtime.h>
#include <hip/hip_bf16.h>

#define N_NODES 50000
#define E_EDGES 800000
#define IN_DIM  256
#define HID     128
#define OUT_DIM 16

#define NBUCK 391    // ceil(50000/128) buckets of 128 nodes (dst>>7)
#define NBLK  128    // blocks for bucket phases A/C
#define P2CAP 4096   // max edges per bucket (mean 2046, sigma ~45)

using frag_ab = __attribute__((ext_vector_type(8))) short;  // 8 bf16
using frag_cd = __attribute__((ext_vector_type(4))) float;  // 4 fp32

static __device__ inline short f2bf(float f) {
    union { float f; unsigned u; } v; v.f = f;
    unsigned r = (v.u + 0x7fffu + ((v.u >> 16) & 1u)) >> 16;
    return (short)r;
}
static __device__ inline float bflo(unsigned u) {
    union { unsigned u; float f; } v; v.u = u << 16; return v.f;
}
static __device__ inline float bfhi(unsigned u) {
    union { unsigned u; float f; } v; v.u = u & 0xffff0000u; return v.f;
}
static __device__ inline unsigned packbf(float a, float b) {
    return (unsigned)(unsigned short)f2bf(a) | ((unsigned)(unsigned short)f2bf(b) << 16);
}

// ================= CSR build: 2-level bucketed counting sort =================

__global__ __launch_bounds__(256) void csr_a(const int* __restrict__ dst,
                                             int* __restrict__ cnt_bb) {
    __shared__ int h[NBUCK];
    int t = threadIdx.x;
    for (int i = t; i < NBUCK; i += 256) h[i] = 0;
    __syncthreads();
    for (int i = blockIdx.x * 256 + t; i < E_EDGES; i += NBLK * 256)
        atomicAdd(&h[dst[i] >> 7], 1);
    __syncthreads();
    for (int i = t; i < NBUCK; i += 256) cnt_bb[i * NBLK + blockIdx.x] = h[i];
}

__global__ __launch_bounds__(NBLK) void csr_b1(int* __restrict__ cnt_bb,
                                               int* __restrict__ btot) {
    __shared__ int sm[NBLK];
    int b = blockIdx.x, t = threadIdx.x;
    int v = cnt_bb[b * NBLK + t];
    sm[t] = v;
    __syncthreads();
    for (int o = 1; o < NBLK; o <<= 1) {
        int u = (t >= o) ? sm[t - o] : 0;
        __syncthreads();
        sm[t] += u;
        __syncthreads();
    }
    cnt_bb[b * NBLK + t] = sm[t] - v;
    if (t == NBLK - 1) btot[b] = sm[t];
}

__global__ __launch_bounds__(512) void csr_b2(const int* __restrict__ btot,
                                              int* __restrict__ bbase) {
    __shared__ int sm[512];
    int t = threadIdx.x;
    int v = (t < NBUCK) ? btot[t] : 0;
    sm[t] = v;
    __syncthreads();
    for (int o = 1; o < 512; o <<= 1) {
        int u = (t >= o) ? sm[t - o] : 0;
        __syncthreads();
        sm[t] += u;
        __syncthreads();
    }
    if (t < NBUCK) bbase[t] = sm[t] - v;
    if (t == 511) bbase[NBUCK] = sm[511];
}

__global__ __launch_bounds__(256) void csr_c(const int* __restrict__ src,
                                             const int* __restrict__ dst,
                                             const int* __restrict__ cnt_bb,
                                             const int* __restrict__ bbase,
                                             unsigned* __restrict__ tmp) {
    __shared__ int run[NBUCK];
    int t = threadIdx.x;
    for (int i = t; i < NBUCK; i += 256)
        run[i] = bbase[i] + cnt_bb[i * NBLK + blockIdx.x];
    __syncthreads();
    for (int i = blockIdx.x * 256 + t; i < E_EDGES; i += NBLK * 256) {
        int d = dst[i];
        int b = d >> 7;
        int pos = atomicAdd(&run[b], 1);
        tmp[pos] = (unsigned)src[i] | ((unsigned)(d & 127) << 17);
    }
}

__global__ __launch_bounds__(256) void csr_p2(const unsigned* __restrict__ tmp,
                                              const int* __restrict__ bbase,
                                              int* __restrict__ rowptr,
                                              float* __restrict__ dinv,
                                              int* __restrict__ ssrc) {
    __shared__ unsigned ed[P2CAP];
    __shared__ int cnt[128];
    __shared__ int off[128];
    int b = blockIdx.x, t = threadIdx.x;
    int base = bbase[b];
    int m = bbase[b + 1] - base;
    if (m > P2CAP) m = P2CAP;
    if (t < 128) cnt[t] = 0;
    __syncthreads();
    for (int i = t; i < m; i += 256) {
        unsigned v = tmp[base + i];
        ed[i] = v;
        atomicAdd(&cnt[v >> 17], 1);
    }
    __syncthreads();
    if (t < 128) off[t] = cnt[t];
    __syncthreads();
    for (int o = 1; o < 128; o <<= 1) {
        int u = (t >= o && t < 128) ? off[t - o] : 0;
        __syncthreads();
        if (t < 128) off[t] += u;
        __syncthreads();
    }
    if (t < 128) {
        int node = b * 128 + t;
        int ex = off[t] - cnt[t];
        if (node < N_NODES) {
            rowptr[node] = base + ex;
            dinv[node] = rsqrtf((float)(cnt[t] + 1));
        }
        off[t] = ex;
    }
    if (b == NBUCK - 1 && t == 0) rowptr[N_NODES] = E_EDGES;
    __syncthreads();
    for (int i = t; i < m; i += 256) {
        unsigned v = ed[i];
        int p = atomicAdd(&off[v >> 17], 1);
        ssrc[base + p] = (int)(v & 0x1FFFF);
    }
}

// ========== W1 -> fragment-major bf16: wtf[f*64+lane] (uint4 = 8 bf16) =====
// fragment f = kt*8+t holds B[k=kt*32+q*8+j][n=t*16+m] for lane=(q<<4)|m.
__global__ void w1_transpose(const float* __restrict__ W, uint4* __restrict__ wtf) {
    int j = blockIdx.x * blockDim.x + threadIdx.x;
    if (j >= 64 * 64) return;
    int f = j >> 6, lane = j & 63;
    int kt = f >> 3, t = f & 7;
    int m = lane & 15, q = lane >> 4;
    int c = t * 16 + m;
    int k0 = kt * 32 + q * 8;
    unsigned p[4];
#pragma unroll
    for (int i = 0; i < 4; ++i)
        p[i] = packbf(W[(k0 + 2 * i) * HID + c], W[(k0 + 2 * i + 1) * HID + c]);
    uint4 v; v.x = p[0]; v.y = p[1]; v.z = p[2]; v.w = p[3];
    wtf[j] = v;
}

// ================= layer-1 GEMM: LDS-staged B, bf16 MFMA ====================
// Block = 8 waves / 128 rows; wt (64 KB) staged to LDS once, fragment-major.
__global__ __launch_bounds__(512) void gemm1_mfma(const float* __restrict__ x,
                                                  const uint4* __restrict__ wtf,
                                                  const float* __restrict__ dinv,
                                                  short* __restrict__ h) {
    __shared__ uint4 lwt[64 * 64];   // 64 fragments x 64 lanes x 16 B = 64 KB
    int tid = threadIdx.x;
#pragma unroll
    for (int i = 0; i < 8; ++i)
        lwt[i * 512 + tid] = wtf[i * 512 + tid];

    int wave = tid >> 6;
    int lane = tid & 63;
    int m = lane & 15;
    int q = lane >> 4;
    int row0 = blockIdx.x * 128 + wave * 16;
    int arow_idx = row0 + m;
    const float4* arow4 = (const float4*)(x + (size_t)(arow_idx < N_NODES ? arow_idx : 0) * IN_DIM);

    frag_ab a[8];
#pragma unroll
    for (int kt = 0; kt < 8; ++kt) {
        float4 f0 = arow4[kt * 8 + q * 2];
        float4 f1 = arow4[kt * 8 + q * 2 + 1];
        a[kt][0] = f2bf(f0.x); a[kt][1] = f2bf(f0.y); a[kt][2] = f2bf(f0.z); a[kt][3] = f2bf(f0.w);
        a[kt][4] = f2bf(f1.x); a[kt][5] = f2bf(f1.y); a[kt][6] = f2bf(f1.z); a[kt][7] = f2bf(f1.w);
    }

    frag_cd acc[8];
#pragma unroll
    for (int t = 0; t < 8; ++t) acc[t] = frag_cd{0.f, 0.f, 0.f, 0.f};

    __syncthreads();

#pragma unroll
    for (int kt = 0; kt < 8; ++kt) {
#pragma unroll
        for (int t = 0; t < 8; ++t) {
            frag_ab b = *(const frag_ab*)&lwt[(kt * 8 + t) * 64 + lane];
            acc[t] = __builtin_amdgcn_mfma_f32_16x16x32_bf16(a[kt], b, acc[t], 0, 0, 0);
        }
    }

    float dv[4];
#pragma unroll
    for (int r = 0; r < 4; ++r) {
        int orow = row0 + q * 4 + r;
        dv[r] = (orow < N_NODES) ? dinv[orow] : 0.f;
    }
#pragma unroll
    for (int t = 0; t < 8; ++t) {
#pragma unroll
        for (int r = 0; r < 4; ++r) {
            int orow = row0 + q * 4 + r;
            if (orow < N_NODES)
                h[(size_t)orow * HID + t * 16 + m] = f2bf(acc[t][r] * dv[r]);
        }
    }
}

// ================= layer-1 pull (node/wave, 2 edges/iter), bf16 out =========
__global__ __launch_bounds__(256) void agg1_pull(const short* __restrict__ h1s,
                                                 const float* __restrict__ dinv,
                                                 const float* __restrict__ b1,
                                                 const int* __restrict__ rowptr,
                                                 const int* __restrict__ ssrc,
                                                 unsigned* __restrict__ out1) {
    int wave = threadIdx.x >> 6;
    int lane = threadIdx.x & 63;
    int node = __builtin_amdgcn_readfirstlane(blockIdx.x * 4 + wave);
    if (node >= N_NODES) return;
    int eo = lane >> 5;
    int g  = lane & 31;

    int lo = rowptr[node], hi = rowptr[node + 1];
    float a0 = 0.f, a1 = 0.f, a2 = 0.f, a3 = 0.f;

    if (eo == 0) {
        uint2 u = *(const uint2*)(h1s + (size_t)node * HID + g * 4);
        a0 = bflo(u.x); a1 = bfhi(u.x); a2 = bflo(u.y); a3 = bfhi(u.y);
    }

    int e = lo;
#pragma unroll 2
    for (; e + 2 <= hi; e += 2) {
        int s0 = ssrc[e];
        int s1 = ssrc[e + 1];
        int s = eo ? s1 : s0;
        uint2 u = *(const uint2*)(h1s + (size_t)s * HID + g * 4);
        a0 += bflo(u.x); a1 += bfhi(u.x); a2 += bflo(u.y); a3 += bfhi(u.y);
    }
    if (e < hi && eo == 0) {
        int s = ssrc[e];
        uint2 u = *(const uint2*)(h1s + (size_t)s * HID + g * 4);
        a0 += bflo(u.x); a1 += bfhi(u.x); a2 += bflo(u.y); a3 += bfhi(u.y);
    }

    a0 += __shfl_xor(a0, 32);
    a1 += __shfl_xor(a1, 32);
    a2 += __shfl_xor(a2, 32);
    a3 += __shfl_xor(a3, 32);

    if (eo == 0) {
        float dd = dinv[node];
        float4 b = *(const float4*)(b1 + g * 4);
        float o0 = fmaxf(fmaf(dd, a0, b.x), 0.f);
        float o1 = fmaxf(fmaf(dd, a1, b.y), 0.f);
        float o2 = fmaxf(fmaf(dd, a2, b.z), 0.f);
        float o3 = fmaxf(fmaf(dd, a3, b.w), 0.f);
        uint2 st; st.x = packbf(o0, o1); st.y = packbf(o2, o3);
        *(uint2*)(out1 + (size_t)node * (HID / 2) + g * 2) = st;
    }
}

// ================= layer-2 GEMM (bf16 in, fp32 out); h2s = (out1@W2)*dinv ===
__global__ void gemm2_kernel(const unsigned* __restrict__ h, const float* __restrict__ W,
                             const float* __restrict__ dinv, float* __restrict__ out, int n) {
    int idx = blockIdx.x * blockDim.x + threadIdx.x;
    if (idx >= n * 4) return;
    int node = idx >> 2;
    int f4 = (idx & 3) << 2;
    const uint2* hr = (const uint2*)(h + (size_t)node * (HID / 2));
    float4 acc = {0.f, 0.f, 0.f, 0.f};
#pragma unroll 8
    for (int k = 0; k < HID; k += 4) {
        uint2 u = hr[k >> 2];
        float x0 = bflo(u.x), x1 = bfhi(u.x), x2 = bflo(u.y), x3 = bfhi(u.y);
        float4 w0 = *(const float4*)(W + (k + 0) * OUT_DIM + f4);
        float4 w1 = *(const float4*)(W + (k + 1) * OUT_DIM + f4);
        float4 w2 = *(const float4*)(W + (k + 2) * OUT_DIM + f4);
        float4 w3 = *(const float4*)(W + (k + 3) * OUT_DIM + f4);
        acc.x += x0 * w0.x + x1 * w1.x + x2 * w2.x + x3 * w3.x;
        acc.y += x0 * w0.y + x1 * w1.y + x2 * w2.y + x3 * w3.y;
        acc.z += x0 * w0.z + x1 * w1.z + x2 * w2.z + x3 * w3.z;
        acc.w += x0 * w0.w + x1 * w1.w + x2 * w2.w + x3 * w3.w;
    }
    float dv = dinv[node];
    acc.x *= dv; acc.y *= dv; acc.z *= dv; acc.w *= dv;
    *(float4*)(out + (size_t)node * OUT_DIM + f4) = acc;
}

// ================= layer-2 pull + fused bias + log_softmax =================
__global__ __launch_bounds__(256) void agg2_pull(const float* __restrict__ h2s,
                                                 const float* __restrict__ dinv,
                                                 const float* __restrict__ b2,
                                                 const int* __restrict__ rowptr,
                                                 const int* __restrict__ ssrc,
                                                 float* __restrict__ out) {
    int wave = threadIdx.x >> 6;
    int lane = threadIdx.x & 63;
    int node = __builtin_amdgcn_readfirstlane(blockIdx.x * 4 + wave);
    if (node >= N_NODES) return;
    int eo = lane >> 4;
    int f  = lane & 15;

    int lo = rowptr[node], hi = rowptr[node + 1];
    float acc = (eo == 0) ? h2s[(size_t)node * OUT_DIM + f] : 0.f;

    int e = lo;
#pragma unroll 2
    for (; e + 4 <= hi; e += 4)
        acc += h2s[(size_t)ssrc[e + eo] * OUT_DIM + f];
    if (e + eo < hi)
        acc += h2s[(size_t)ssrc[e + eo] * OUT_DIM + f];

    acc += __shfl_xor(acc, 16);
    acc += __shfl_xor(acc, 32);

    float dd = dinv[node];
    float v = fmaf(dd, acc, b2[f]);

    float m = v;
#pragma unroll
    for (int msk = 1; msk < 16; msk <<= 1) m = fmaxf(m, __shfl_xor(m, msk));
    float ex = __expf(v - m);
    float ssum = ex;
#pragma unroll
    for (int msk = 1; msk < 16; msk <<= 1) ssum += __shfl_xor(ssum, msk);
    if (eo == 0) out[(size_t)node * OUT_DIM + f] = v - m - __logf(ssum);
}

extern "C" void kernel_launch(void* const* d_in, const int* in_sizes, int n_in,
                              void* d_out, int out_size, void* d_ws, size_t ws_size,
                              hipStream_t stream) {
    const float* x  = (const float*)d_in[0];
    const int*   ei = (const int*)d_in[1];
    const float* W1 = (const float*)d_in[2];
    const float* b1 = (const float*)d_in[3];
    const float* W2 = (const float*)d_in[4];
    const float* b2 = (const float*)d_in[5];
    float* out = (float*)d_out;

    const int n = N_NODES;
    const int e = E_EDGES;
    const int* srcp = ei;        // edge_index[0]
    const int* dstp = ei + e;    // edge_index[1]

    // workspace layout
    char* w = (char*)d_ws;
    int*      cnt_bb = (int*)w;        w += (size_t)NBUCK * NBLK * 4;
    int*      btot   = (int*)w;        w += (size_t)NBUCK * 4;
    int*      bbase  = (int*)w;        w += (size_t)(NBUCK + 1) * 4;
    int*      rowptr = (int*)w;        w += (size_t)(n + 1) * 4;
    float*    dinv   = (float*)w;      w += (size_t)n * 4;
    unsigned* tmp    = (unsigned*)w;   w += (size_t)e * 4;
    int*      ssrc   = (int*)w;        w += (size_t)e * 4;
    uint4*    wtf    = (uint4*)w;      w += (size_t)64 * 64 * 16;   // frag-major bf16 W1
    short*    h1s    = (short*)w;      w += (size_t)n * HID * 2;    // bf16, pre-scaled
    unsigned* out1   = (unsigned*)w;   w += (size_t)n * HID * 2;    // bf16 packed
    float*    h2s    = (float*)w;      w += (size_t)n * OUT_DIM * 4;

    const int B = 256;
    auto blk = [](long long total, int b) { return (int)((total + b - 1) / b); };

    // CSR build (bucketed counting sort; also produces rowptr + dinv)
    csr_a<<<NBLK, 256, 0, stream>>>(dstp, cnt_bb);
    csr_b1<<<NBUCK, NBLK, 0, stream>>>(cnt_bb, btot);
    csr_b2<<<1, 512, 0, stream>>>(btot, bbase);
    csr_c<<<NBLK, 256, 0, stream>>>(srcp, dstp, cnt_bb, bbase, tmp);
    csr_p2<<<NBUCK, 256, 0, stream>>>(tmp, bbase, rowptr, dinv, ssrc);

    // layer 1
    w1_transpose<<<16, 256, 0, stream>>>(W1, wtf);
    gemm1_mfma<<<blk(n, 128), 512, 0, stream>>>(x, wtf, dinv, h1s);
    agg1_pull<<<blk(n, 4), 256, 0, stream>>>(h1s, dinv, b1, rowptr, ssrc, out1);

    // layer 2
    gemm2_kernel<<<blk((long long)n * 4, B), B, 0, stream>>>(out1, W2, dinv, h2s, n);
    agg2_pull<<<blk(n, 4), 256, 0, stream>>>(h2s, dinv, b2, rowptr, ssrc, out);
}

// Round 7
// 207.389 us; speedup vs baseline: 4.5586x; 1.0537x over previous
//
#include <hip/hip_runtime.h>
#include <hip/hip_bf16.h>

#define N_NODES 50000
#define E_EDGES 800000
#define IN_DIM  256
#define HID     128
#define OUT_DIM 16

#define NBUCK 391    // ceil(50000/128) buckets of 128 nodes (dst>>7)
#define NBLK  128    // blocks for bucket phases A/C
#define P2CAP 4096   // max edges per bucket (mean 2046, sigma ~45)

using frag_ab = __attribute__((ext_vector_type(8))) short;  // 8 bf16
using frag_cd = __attribute__((ext_vector_type(4))) float;  // 4 fp32

static __device__ inline short f2bf(float f) {
    union { float f; unsigned u; } v; v.f = f;
    unsigned r = (v.u + 0x7fffu + ((v.u >> 16) & 1u)) >> 16;
    return (short)r;
}
static __device__ inline float bflo(unsigned u) {
    union { unsigned u; float f; } v; v.u = u << 16; return v.f;
}
static __device__ inline float bfhi(unsigned u) {
    union { unsigned u; float f; } v; v.u = u & 0xffff0000u; return v.f;
}
static __device__ inline unsigned packbf(float a, float b) {
    return (unsigned)(unsigned short)f2bf(a) | ((unsigned)(unsigned short)f2bf(b) << 16);
}

// ================= CSR build: 2-level bucketed counting sort =================

__global__ __launch_bounds__(256) void csr_a(const int4* __restrict__ dst4,
                                             int* __restrict__ cnt_bb) {
    __shared__ int h[NBUCK];
    int t = threadIdx.x;
    for (int i = t; i < NBUCK; i += 256) h[i] = 0;
    __syncthreads();
    for (int i = blockIdx.x * 256 + t; i < E_EDGES / 4; i += NBLK * 256) {
        int4 d = dst4[i];
        atomicAdd(&h[d.x >> 7], 1);
        atomicAdd(&h[d.y >> 7], 1);
        atomicAdd(&h[d.z >> 7], 1);
        atomicAdd(&h[d.w >> 7], 1);
    }
    __syncthreads();
    for (int i = t; i < NBUCK; i += 256) cnt_bb[i * NBLK + blockIdx.x] = h[i];
}

__global__ __launch_bounds__(NBLK) void csr_b1(int* __restrict__ cnt_bb,
                                               int* __restrict__ btot) {
    __shared__ int sm[NBLK];
    int b = blockIdx.x, t = threadIdx.x;
    int v = cnt_bb[b * NBLK + t];
    sm[t] = v;
    __syncthreads();
    for (int o = 1; o < NBLK; o <<= 1) {
        int u = (t >= o) ? sm[t - o] : 0;
        __syncthreads();
        sm[t] += u;
        __syncthreads();
    }
    cnt_bb[b * NBLK + t] = sm[t] - v;
    if (t == NBLK - 1) btot[b] = sm[t];
}

__global__ __launch_bounds__(512) void csr_b2(const int* __restrict__ btot,
                                              int* __restrict__ bbase) {
    __shared__ int sm[512];
    int t = threadIdx.x;
    int v = (t < NBUCK) ? btot[t] : 0;
    sm[t] = v;
    __syncthreads();
    for (int o = 1; o < 512; o <<= 1) {
        int u = (t >= o) ? sm[t - o] : 0;
        __syncthreads();
        sm[t] += u;
        __syncthreads();
    }
    if (t < NBUCK) bbase[t] = sm[t] - v;
    if (t == 511) bbase[NBUCK] = sm[511];
}

__global__ __launch_bounds__(256) void csr_c(const int4* __restrict__ src4,
                                             const int4* __restrict__ dst4,
                                             const int* __restrict__ cnt_bb,
                                             const int* __restrict__ bbase,
                                             unsigned* __restrict__ tmp) {
    __shared__ int run[NBUCK];
    int t = threadIdx.x;
    for (int i = t; i < NBUCK; i += 256)
        run[i] = bbase[i] + cnt_bb[i * NBLK + blockIdx.x];
    __syncthreads();
    for (int i = blockIdx.x * 256 + t; i < E_EDGES / 4; i += NBLK * 256) {
        int4 d = dst4[i];
        int4 s = src4[i];
        int p0 = atomicAdd(&run[d.x >> 7], 1);
        tmp[p0] = (unsigned)s.x | ((unsigned)(d.x & 127) << 17);
        int p1 = atomicAdd(&run[d.y >> 7], 1);
        tmp[p1] = (unsigned)s.y | ((unsigned)(d.y & 127) << 17);
        int p2 = atomicAdd(&run[d.z >> 7], 1);
        tmp[p2] = (unsigned)s.z | ((unsigned)(d.z & 127) << 17);
        int p3 = atomicAdd(&run[d.w >> 7], 1);
        tmp[p3] = (unsigned)s.w | ((unsigned)(d.w & 127) << 17);
    }
}

__global__ __launch_bounds__(256) void csr_p2(const unsigned* __restrict__ tmp,
                                              const int* __restrict__ bbase,
                                              int* __restrict__ rowptr,
                                              float* __restrict__ dinv,
                                              int* __restrict__ ssrc) {
    __shared__ unsigned ed[P2CAP];
    __shared__ int cnt[128];
    __shared__ int off[128];
    int b = blockIdx.x, t = threadIdx.x;
    int base = bbase[b];
    int m = bbase[b + 1] - base;
    if (m > P2CAP) m = P2CAP;
    if (t < 128) cnt[t] = 0;
    __syncthreads();
    for (int i = t; i < m; i += 256) {
        unsigned v = tmp[base + i];
        ed[i] = v;
        atomicAdd(&cnt[v >> 17], 1);
    }
    __syncthreads();
    if (t < 128) off[t] = cnt[t];
    __syncthreads();
    for (int o = 1; o < 128; o <<= 1) {
        int u = (t >= o && t < 128) ? off[t - o] : 0;
        __syncthreads();
        if (t < 128) off[t] += u;
        __syncthreads();
    }
    if (t < 128) {
        int node = b * 128 + t;
        int ex = off[t] - cnt[t];
        if (node < N_NODES) {
            rowptr[node] = base + ex;
            dinv[node] = rsqrtf((float)(cnt[t] + 1));
        }
        off[t] = ex;
    }
    if (b == NBUCK - 1 && t == 0) rowptr[N_NODES] = E_EDGES;
    __syncthreads();
    for (int i = t; i < m; i += 256) {
        unsigned v = ed[i];
        int p = atomicAdd(&off[v >> 17], 1);
        ssrc[base + p] = (int)(v & 0x1FFFF);
    }
}

// ========== W1 -> fragment-major bf16: wtf[f*64+lane] (uint4 = 8 bf16) =====
__global__ void w1_transpose(const float* __restrict__ W, uint4* __restrict__ wtf) {
    int j = blockIdx.x * blockDim.x + threadIdx.x;
    if (j >= 64 * 64) return;
    int f = j >> 6, lane = j & 63;
    int kt = f >> 3, t = f & 7;
    int m = lane & 15, q = lane >> 4;
    int c = t * 16 + m;
    int k0 = kt * 32 + q * 8;
    unsigned p[4];
#pragma unroll
    for (int i = 0; i < 4; ++i)
        p[i] = packbf(W[(k0 + 2 * i) * HID + c], W[(k0 + 2 * i + 1) * HID + c]);
    uint4 v; v.x = p[0]; v.y = p[1]; v.z = p[2]; v.w = p[3];
    wtf[j] = v;
}

// ================= layer-1 GEMM: LDS-staged B, bf16 MFMA ====================
__global__ __launch_bounds__(512) void gemm1_mfma(const float* __restrict__ x,
                                                  const uint4* __restrict__ wtf,
                                                  const float* __restrict__ dinv,
                                                  short* __restrict__ h) {
    __shared__ uint4 lwt[64 * 64];   // 64 KB
    int tid = threadIdx.x;
#pragma unroll
    for (int i = 0; i < 8; ++i)
        lwt[i * 512 + tid] = wtf[i * 512 + tid];

    int wave = tid >> 6;
    int lane = tid & 63;
    int m = lane & 15;
    int q = lane >> 4;
    int row0 = blockIdx.x * 128 + wave * 16;
    int arow_idx = row0 + m;
    const float4* arow4 = (const float4*)(x + (size_t)(arow_idx < N_NODES ? arow_idx : 0) * IN_DIM);

    frag_ab a[8];
#pragma unroll
    for (int kt = 0; kt < 8; ++kt) {
        float4 f0 = arow4[kt * 8 + q * 2];
        float4 f1 = arow4[kt * 8 + q * 2 + 1];
        a[kt][0] = f2bf(f0.x); a[kt][1] = f2bf(f0.y); a[kt][2] = f2bf(f0.z); a[kt][3] = f2bf(f0.w);
        a[kt][4] = f2bf(f1.x); a[kt][5] = f2bf(f1.y); a[kt][6] = f2bf(f1.z); a[kt][7] = f2bf(f1.w);
    }

    frag_cd acc[8];
#pragma unroll
    for (int t = 0; t < 8; ++t) acc[t] = frag_cd{0.f, 0.f, 0.f, 0.f};

    __syncthreads();

#pragma unroll
    for (int kt = 0; kt < 8; ++kt) {
#pragma unroll
        for (int t = 0; t < 8; ++t) {
            frag_ab b = *(const frag_ab*)&lwt[(kt * 8 + t) * 64 + lane];
            acc[t] = __builtin_amdgcn_mfma_f32_16x16x32_bf16(a[kt], b, acc[t], 0, 0, 0);
        }
    }

    float dv[4];
#pragma unroll
    for (int r = 0; r < 4; ++r) {
        int orow = row0 + q * 4 + r;
        dv[r] = (orow < N_NODES) ? dinv[orow] : 0.f;
    }
#pragma unroll
    for (int t = 0; t < 8; ++t) {
#pragma unroll
        for (int r = 0; r < 4; ++r) {
            int orow = row0 + q * 4 + r;
            if (orow < N_NODES)
                h[(size_t)orow * HID + t * 16 + m] = f2bf(acc[t][r] * dv[r]);
        }
    }
}

// ===== layer-1 pull: node/wave, 4 edges/iter, uint4 gathers, bf16 out ======
// lane = eo*16 + g; eo in [0,4) picks edge of quad, g in [0,16) picks 8
// features (uint4 = 16 B). 16 lanes x 16 B = full 256 B row per edge.
__global__ __launch_bounds__(256) void agg1_pull(const short* __restrict__ h1s,
                                                 const float* __restrict__ dinv,
                                                 const float* __restrict__ b1,
                                                 const int* __restrict__ rowptr,
                                                 const int* __restrict__ ssrc,
                                                 unsigned* __restrict__ out1) {
    int wave = threadIdx.x >> 6;
    int lane = threadIdx.x & 63;
    int node = __builtin_amdgcn_readfirstlane(blockIdx.x * 4 + wave);
    if (node >= N_NODES) return;
    int eo = lane >> 4;       // edge within quad
    int g  = lane & 15;       // feature octet: features 8g..8g+7

    int lo = rowptr[node], hi = rowptr[node + 1];
    float a0 = 0.f, a1 = 0.f, a2 = 0.f, a3 = 0.f;
    float a4 = 0.f, a5 = 0.f, a6 = 0.f, a7 = 0.f;

    if (eo == 0) {   // self-loop row
        uint4 u = *(const uint4*)(h1s + (size_t)node * HID + g * 8);
        a0 = bflo(u.x); a1 = bfhi(u.x); a2 = bflo(u.y); a3 = bfhi(u.y);
        a4 = bflo(u.z); a5 = bfhi(u.z); a6 = bflo(u.w); a7 = bfhi(u.w);
    }

    int e = lo;
#pragma unroll 2
    for (; e + 4 <= hi; e += 4) {
        int s = ssrc[e + eo];
        uint4 u = *(const uint4*)(h1s + (size_t)s * HID + g * 8);
        a0 += bflo(u.x); a1 += bfhi(u.x); a2 += bflo(u.y); a3 += bfhi(u.y);
        a4 += bflo(u.z); a5 += bfhi(u.z); a6 += bflo(u.w); a7 += bfhi(u.w);
    }
    if (eo < hi - e) {   // 0..3 leftover edges
        int s = ssrc[e + eo];
        uint4 u = *(const uint4*)(h1s + (size_t)s * HID + g * 8);
        a0 += bflo(u.x); a1 += bfhi(u.x); a2 += bflo(u.y); a3 += bfhi(u.y);
        a4 += bflo(u.z); a5 += bfhi(u.z); a6 += bflo(u.w); a7 += bfhi(u.w);
    }

    // combine the 4 edge groups (lanes differing in bits 4,5)
    a0 += __shfl_xor(a0, 16); a1 += __shfl_xor(a1, 16);
    a2 += __shfl_xor(a2, 16); a3 += __shfl_xor(a3, 16);
    a4 += __shfl_xor(a4, 16); a5 += __shfl_xor(a5, 16);
    a6 += __shfl_xor(a6, 16); a7 += __shfl_xor(a7, 16);
    a0 += __shfl_xor(a0, 32); a1 += __shfl_xor(a1, 32);
    a2 += __shfl_xor(a2, 32); a3 += __shfl_xor(a3, 32);
    a4 += __shfl_xor(a4, 32); a5 += __shfl_xor(a5, 32);
    a6 += __shfl_xor(a6, 32); a7 += __shfl_xor(a7, 32);

    if (eo == 0) {
        float dd = dinv[node];
        float4 bA = *(const float4*)(b1 + g * 8);
        float4 bB = *(const float4*)(b1 + g * 8 + 4);
        float o0 = fmaxf(fmaf(dd, a0, bA.x), 0.f);
        float o1 = fmaxf(fmaf(dd, a1, bA.y), 0.f);
        float o2 = fmaxf(fmaf(dd, a2, bA.z), 0.f);
        float o3 = fmaxf(fmaf(dd, a3, bA.w), 0.f);
        float o4 = fmaxf(fmaf(dd, a4, bB.x), 0.f);
        float o5 = fmaxf(fmaf(dd, a5, bB.y), 0.f);
        float o6 = fmaxf(fmaf(dd, a6, bB.z), 0.f);
        float o7 = fmaxf(fmaf(dd, a7, bB.w), 0.f);
        uint4 st;
        st.x = packbf(o0, o1); st.y = packbf(o2, o3);
        st.z = packbf(o4, o5); st.w = packbf(o6, o7);
        *(uint4*)(out1 + (size_t)node * (HID / 2) + g * 4) = st;
    }
}

// ================= layer-2 GEMM (bf16 in, fp32 out); h2s = (out1@W2)*dinv ===
__global__ void gemm2_kernel(const unsigned* __restrict__ h, const float* __restrict__ W,
                             const float* __restrict__ dinv, float* __restrict__ out, int n) {
    int idx = blockIdx.x * blockDim.x + threadIdx.x;
    if (idx >= n * 4) return;
    int node = idx >> 2;
    int f4 = (idx & 3) << 2;
    const uint2* hr = (const uint2*)(h + (size_t)node * (HID / 2));
    float4 acc = {0.f, 0.f, 0.f, 0.f};
#pragma unroll 8
    for (int k = 0; k < HID; k += 4) {
        uint2 u = hr[k >> 2];
        float x0 = bflo(u.x), x1 = bfhi(u.x), x2 = bflo(u.y), x3 = bfhi(u.y);
        float4 w0 = *(const float4*)(W + (k + 0) * OUT_DIM + f4);
        float4 w1 = *(const float4*)(W + (k + 1) * OUT_DIM + f4);
        float4 w2 = *(const float4*)(W + (k + 2) * OUT_DIM + f4);
        float4 w3 = *(const float4*)(W + (k + 3) * OUT_DIM + f4);
        acc.x += x0 * w0.x + x1 * w1.x + x2 * w2.x + x3 * w3.x;
        acc.y += x0 * w0.y + x1 * w1.y + x2 * w2.y + x3 * w3.y;
        acc.z += x0 * w0.z + x1 * w1.z + x2 * w2.z + x3 * w3.z;
        acc.w += x0 * w0.w + x1 * w1.w + x2 * w2.w + x3 * w3.w;
    }
    float dv = dinv[node];
    acc.x *= dv; acc.y *= dv; acc.z *= dv; acc.w *= dv;
    *(float4*)(out + (size_t)node * OUT_DIM + f4) = acc;
}

// ================= layer-2 pull + fused bias + log_softmax =================
__global__ __launch_bounds__(256) void agg2_pull(const float* __restrict__ h2s,
                                                 const float* __restrict__ dinv,
                                                 const float* __restrict__ b2,
                                                 const int* __restrict__ rowptr,
                                                 const int* __restrict__ ssrc,
                                                 float* __restrict__ out) {
    int wave = threadIdx.x >> 6;
    int lane = threadIdx.x & 63;
    int node = __builtin_amdgcn_readfirstlane(blockIdx.x * 4 + wave);
    if (node >= N_NODES) return;
    int eo = lane >> 4;
    int f  = lane & 15;

    int lo = rowptr[node], hi = rowptr[node + 1];
    float acc = (eo == 0) ? h2s[(size_t)node * OUT_DIM + f] : 0.f;

    int e = lo;
#pragma unroll 2
    for (; e + 4 <= hi; e += 4)
        acc += h2s[(size_t)ssrc[e + eo] * OUT_DIM + f];
    if (e + eo < hi)
        acc += h2s[(size_t)ssrc[e + eo] * OUT_DIM + f];

    acc += __shfl_xor(acc, 16);
    acc += __shfl_xor(acc, 32);

    float dd = dinv[node];
    float v = fmaf(dd, acc, b2[f]);

    float m = v;
#pragma unroll
    for (int msk = 1; msk < 16; msk <<= 1) m = fmaxf(m, __shfl_xor(m, msk));
    float ex = __expf(v - m);
    float ssum = ex;
#pragma unroll
    for (int msk = 1; msk < 16; msk <<= 1) ssum += __shfl_xor(ssum, msk);
    if (eo == 0) out[(size_t)node * OUT_DIM + f] = v - m - __logf(ssum);
}

extern "C" void kernel_launch(void* const* d_in, const int* in_sizes, int n_in,
                              void* d_out, int out_size, void* d_ws, size_t ws_size,
                              hipStream_t stream) {
    const float* x  = (const float*)d_in[0];
    const int*   ei = (const int*)d_in[1];
    const float* W1 = (const float*)d_in[2];
    const float* b1 = (const float*)d_in[3];
    const float* W2 = (const float*)d_in[4];
    const float* b2 = (const float*)d_in[5];
    float* out = (float*)d_out;

    const int n = N_NODES;
    const int e = E_EDGES;
    const int* srcp = ei;        // edge_index[0]
    const int* dstp = ei + e;    // edge_index[1]

    // workspace layout
    char* w = (char*)d_ws;
    int*      cnt_bb = (int*)w;        w += (size_t)NBUCK * NBLK * 4;
    int*      btot   = (int*)w;        w += (size_t)NBUCK * 4;
    int*      bbase  = (int*)w;        w += (size_t)(NBUCK + 1) * 4;
    int*      rowptr = (int*)w;        w += (size_t)(n + 1) * 4;
    float*    dinv   = (float*)w;      w += (size_t)n * 4;
    unsigned* tmp    = (unsigned*)w;   w += (size_t)e * 4;
    int*      ssrc   = (int*)w;        w += (size_t)e * 4;
    uint4*    wtf    = (uint4*)w;      w += (size_t)64 * 64 * 16;   // frag-major bf16 W1
    short*    h1s    = (short*)w;      w += (size_t)n * HID * 2;    // bf16, pre-scaled
    unsigned* out1   = (unsigned*)w;   w += (size_t)n * HID * 2;    // bf16 packed
    float*    h2s    = (float*)w;      w += (size_t)n * OUT_DIM * 4;

    const int B = 256;
    auto blk = [](long long total, int b) { return (int)((total + b - 1) / b); };

    // CSR build (bucketed counting sort; also produces rowptr + dinv)
    csr_a<<<NBLK, 256, 0, stream>>>((const int4*)dstp, cnt_bb);
    csr_b1<<<NBUCK, NBLK, 0, stream>>>(cnt_bb, btot);
    csr_b2<<<1, 512, 0, stream>>>(btot, bbase);
    csr_c<<<NBLK, 256, 0, stream>>>((const int4*)srcp, (const int4*)dstp, cnt_bb, bbase, tmp);
    csr_p2<<<NBUCK, 256, 0, stream>>>(tmp, bbase, rowptr, dinv, ssrc);

    // layer 1
    w1_transpose<<<16, 256, 0, stream>>>(W1, wtf);
    gemm1_mfma<<<blk(n, 128), 512, 0, stream>>>(x, wtf, dinv, h1s);
    agg1_pull<<<blk(n, 4), 256, 0, stream>>>(h1s, dinv, b1, rowptr, ssrc, out1);

    // layer 2
    gemm2_kernel<<<blk((long long)n * 4, B), B, 0, stream>>>(out1, W2, dinv, h2s, n);
    agg2_pull<<<blk(n, 4), 256, 0, stream>>>(h2s, dinv, b2, rowptr, ssrc, out);
}

// Round 8
// 199.417 us; speedup vs baseline: 4.7409x; 1.0400x over previous
//
#include <hip/hip_runtime.h>
#include <hip/hip_bf16.h>

#define N_NODES 50000
#define E_EDGES 800000
#define IN_DIM  256
#define HID     128
#define OUT_DIM 16

#define NBUCK 391    // ceil(50000/128) buckets of 128 nodes (dst>>7)
#define NBLK  128    // blocks for bucket phases A/C
#define P2CAP 4096   // max edges per bucket (mean 2046, sigma ~45)

using frag_ab = __attribute__((ext_vector_type(8))) short;  // 8 bf16
using frag_cd = __attribute__((ext_vector_type(4))) float;  // 4 fp32

static __device__ inline short f2bf(float f) {
    union { float f; unsigned u; } v; v.f = f;
    unsigned r = (v.u + 0x7fffu + ((v.u >> 16) & 1u)) >> 16;
    return (short)r;
}
static __device__ inline float bflo(unsigned u) {
    union { unsigned u; float f; } v; v.u = u << 16; return v.f;
}
static __device__ inline float bfhi(unsigned u) {
    union { unsigned u; float f; } v; v.u = u & 0xffff0000u; return v.f;
}
static __device__ inline unsigned packbf(float a, float b) {
    return (unsigned)(unsigned short)f2bf(a) | ((unsigned)(unsigned short)f2bf(b) << 16);
}

// ================= CSR build: 2-level bucketed counting sort =================

__global__ __launch_bounds__(256) void csr_a(const int4* __restrict__ dst4,
                                             int* __restrict__ cnt_bb) {
    __shared__ int h[NBUCK];
    int t = threadIdx.x;
    for (int i = t; i < NBUCK; i += 256) h[i] = 0;
    __syncthreads();
    for (int i = blockIdx.x * 256 + t; i < E_EDGES / 4; i += NBLK * 256) {
        int4 d = dst4[i];
        atomicAdd(&h[d.x >> 7], 1);
        atomicAdd(&h[d.y >> 7], 1);
        atomicAdd(&h[d.z >> 7], 1);
        atomicAdd(&h[d.w >> 7], 1);
    }
    __syncthreads();
    for (int i = t; i < NBUCK; i += 256) cnt_bb[i * NBLK + blockIdx.x] = h[i];
}

__global__ __launch_bounds__(NBLK) void csr_b1(int* __restrict__ cnt_bb,
                                               int* __restrict__ btot) {
    __shared__ int sm[NBLK];
    int b = blockIdx.x, t = threadIdx.x;
    int v = cnt_bb[b * NBLK + t];
    sm[t] = v;
    __syncthreads();
    for (int o = 1; o < NBLK; o <<= 1) {
        int u = (t >= o) ? sm[t - o] : 0;
        __syncthreads();
        sm[t] += u;
        __syncthreads();
    }
    cnt_bb[b * NBLK + t] = sm[t] - v;
    if (t == NBLK - 1) btot[b] = sm[t];
}

// blocks 0..7: W1 -> fragment-major bf16 transpose (512 thr each)
// block  8  : exclusive scan of bucket totals -> bbase
__global__ __launch_bounds__(512) void csr_b2_w1t(const int* __restrict__ btot,
                                                  int* __restrict__ bbase,
                                                  const float* __restrict__ W,
                                                  uint4* __restrict__ wtf) {
    int t = threadIdx.x;
    if (blockIdx.x < 8) {
        int j = blockIdx.x * 512 + t;   // 4096 fragments-lanes total
        int f = j >> 6, lane = j & 63;
        int kt = f >> 3, tt = f & 7;
        int m = lane & 15, q = lane >> 4;
        int c = tt * 16 + m;
        int k0 = kt * 32 + q * 8;
        unsigned p[4];
#pragma unroll
        for (int i = 0; i < 4; ++i)
            p[i] = packbf(W[(k0 + 2 * i) * HID + c], W[(k0 + 2 * i + 1) * HID + c]);
        uint4 v; v.x = p[0]; v.y = p[1]; v.z = p[2]; v.w = p[3];
        wtf[j] = v;
        return;
    }
    __shared__ int sm[512];
    int v = (t < NBUCK) ? btot[t] : 0;
    sm[t] = v;
    __syncthreads();
    for (int o = 1; o < 512; o <<= 1) {
        int u = (t >= o) ? sm[t - o] : 0;
        __syncthreads();
        sm[t] += u;
        __syncthreads();
    }
    if (t < NBUCK) bbase[t] = sm[t] - v;
    if (t == 511) bbase[NBUCK] = sm[511];
}

__global__ __launch_bounds__(256) void csr_c(const int4* __restrict__ src4,
                                             const int4* __restrict__ dst4,
                                             const int* __restrict__ cnt_bb,
                                             const int* __restrict__ bbase,
                                             unsigned* __restrict__ tmp) {
    __shared__ int run[NBUCK];
    int t = threadIdx.x;
    for (int i = t; i < NBUCK; i += 256)
        run[i] = bbase[i] + cnt_bb[i * NBLK + blockIdx.x];
    __syncthreads();
    for (int i = blockIdx.x * 256 + t; i < E_EDGES / 4; i += NBLK * 256) {
        int4 d = dst4[i];
        int4 s = src4[i];
        int p0 = atomicAdd(&run[d.x >> 7], 1);
        tmp[p0] = (unsigned)s.x | ((unsigned)(d.x & 127) << 17);
        int p1 = atomicAdd(&run[d.y >> 7], 1);
        tmp[p1] = (unsigned)s.y | ((unsigned)(d.y & 127) << 17);
        int p2 = atomicAdd(&run[d.z >> 7], 1);
        tmp[p2] = (unsigned)s.z | ((unsigned)(d.z & 127) << 17);
        int p3 = atomicAdd(&run[d.w >> 7], 1);
        tmp[p3] = (unsigned)s.w | ((unsigned)(d.w & 127) << 17);
    }
}

__global__ __launch_bounds__(256) void csr_p2(const unsigned* __restrict__ tmp,
                                              const int* __restrict__ bbase,
                                              int* __restrict__ rowptr,
                                              float* __restrict__ dinv,
                                              int* __restrict__ ssrc) {
    __shared__ unsigned ed[P2CAP];
    __shared__ int cnt[128];
    __shared__ int off[128];
    int b = blockIdx.x, t = threadIdx.x;
    int base = bbase[b];
    int m = bbase[b + 1] - base;
    if (m > P2CAP) m = P2CAP;
    if (t < 128) cnt[t] = 0;
    __syncthreads();
    for (int i = t; i < m; i += 256) {
        unsigned v = tmp[base + i];
        ed[i] = v;
        atomicAdd(&cnt[v >> 17], 1);
    }
    __syncthreads();
    if (t < 128) off[t] = cnt[t];
    __syncthreads();
    for (int o = 1; o < 128; o <<= 1) {
        int u = (t >= o && t < 128) ? off[t - o] : 0;
        __syncthreads();
        if (t < 128) off[t] += u;
        __syncthreads();
    }
    if (t < 128) {
        int node = b * 128 + t;
        int ex = off[t] - cnt[t];
        if (node < N_NODES) {
            rowptr[node] = base + ex;
            dinv[node] = rsqrtf((float)(cnt[t] + 1));
        }
        off[t] = ex;
    }
    if (b == NBUCK - 1 && t == 0) rowptr[N_NODES] = E_EDGES;
    __syncthreads();
    for (int i = t; i < m; i += 256) {
        unsigned v = ed[i];
        int p = atomicAdd(&off[v >> 17], 1);
        ssrc[base + p] = (int)(v & 0x1FFFF);
    }
}

// ================= layer-1 GEMM: LDS-staged B, bf16 MFMA ====================
__global__ __launch_bounds__(512) void gemm1_mfma(const float* __restrict__ x,
                                                  const uint4* __restrict__ wtf,
                                                  const float* __restrict__ dinv,
                                                  short* __restrict__ h) {
    __shared__ uint4 lwt[64 * 64];   // 64 KB
    int tid = threadIdx.x;
#pragma unroll
    for (int i = 0; i < 8; ++i)
        lwt[i * 512 + tid] = wtf[i * 512 + tid];

    int wave = tid >> 6;
    int lane = tid & 63;
    int m = lane & 15;
    int q = lane >> 4;
    int row0 = blockIdx.x * 128 + wave * 16;
    int arow_idx = row0 + m;
    const float4* arow4 = (const float4*)(x + (size_t)(arow_idx < N_NODES ? arow_idx : 0) * IN_DIM);

    frag_ab a[8];
#pragma unroll
    for (int kt = 0; kt < 8; ++kt) {
        float4 f0 = arow4[kt * 8 + q * 2];
        float4 f1 = arow4[kt * 8 + q * 2 + 1];
        a[kt][0] = f2bf(f0.x); a[kt][1] = f2bf(f0.y); a[kt][2] = f2bf(f0.z); a[kt][3] = f2bf(f0.w);
        a[kt][4] = f2bf(f1.x); a[kt][5] = f2bf(f1.y); a[kt][6] = f2bf(f1.z); a[kt][7] = f2bf(f1.w);
    }

    frag_cd acc[8];
#pragma unroll
    for (int t = 0; t < 8; ++t) acc[t] = frag_cd{0.f, 0.f, 0.f, 0.f};

    __syncthreads();

#pragma unroll
    for (int kt = 0; kt < 8; ++kt) {
#pragma unroll
        for (int t = 0; t < 8; ++t) {
            frag_ab b = *(const frag_ab*)&lwt[(kt * 8 + t) * 64 + lane];
            acc[t] = __builtin_amdgcn_mfma_f32_16x16x32_bf16(a[kt], b, acc[t], 0, 0, 0);
        }
    }

    float dv[4];
#pragma unroll
    for (int r = 0; r < 4; ++r) {
        int orow = row0 + q * 4 + r;
        dv[r] = (orow < N_NODES) ? dinv[orow] : 0.f;
    }
#pragma unroll
    for (int t = 0; t < 8; ++t) {
#pragma unroll
        for (int r = 0; r < 4; ++r) {
            int orow = row0 + q * 4 + r;
            if (orow < N_NODES)
                h[(size_t)orow * HID + t * 16 + m] = f2bf(acc[t][r] * dv[r]);
        }
    }
}

// ===== layer-1 pull + fused layer-2 transform ===============================
// Gathers h1s rows (4 edges/iter, uint4/lane), reduces, applies bias+ReLU,
// then immediately computes h2s[node] = (out1_row @ W2) * dinv[node] using
// LDS-staged row + W2 — out1 never touches global memory.
__global__ __launch_bounds__(256) void agg1_fused(const short* __restrict__ h1s,
                                                  const float* __restrict__ dinv,
                                                  const float* __restrict__ b1,
                                                  const float* __restrict__ W2,
                                                  const int* __restrict__ rowptr,
                                                  const int* __restrict__ ssrc,
                                                  float* __restrict__ h2s) {
    __shared__ float sw2[HID * OUT_DIM];   // 8 KB, [k][f] row-major
    __shared__ float srow[4][HID];         // 2 KB: one relu'd row per wave
    int tid = threadIdx.x;
#pragma unroll
    for (int i = 0; i < 8; ++i) sw2[i * 256 + tid] = W2[i * 256 + tid];
    __syncthreads();

    int wave = tid >> 6;
    int lane = tid & 63;
    int node = __builtin_amdgcn_readfirstlane(blockIdx.x * 4 + wave);
    if (node >= N_NODES) return;
    int eo = lane >> 4;       // edge within quad
    int g  = lane & 15;       // feature octet: features 8g..8g+7

    int lo = rowptr[node], hi = rowptr[node + 1];
    float a0 = 0.f, a1 = 0.f, a2 = 0.f, a3 = 0.f;
    float a4 = 0.f, a5 = 0.f, a6 = 0.f, a7 = 0.f;

    if (eo == 0) {   // self-loop row
        uint4 u = *(const uint4*)(h1s + (size_t)node * HID + g * 8);
        a0 = bflo(u.x); a1 = bfhi(u.x); a2 = bflo(u.y); a3 = bfhi(u.y);
        a4 = bflo(u.z); a5 = bfhi(u.z); a6 = bflo(u.w); a7 = bfhi(u.w);
    }

    int e = lo;
#pragma unroll 2
    for (; e + 4 <= hi; e += 4) {
        int s = ssrc[e + eo];
        uint4 u = *(const uint4*)(h1s + (size_t)s * HID + g * 8);
        a0 += bflo(u.x); a1 += bfhi(u.x); a2 += bflo(u.y); a3 += bfhi(u.y);
        a4 += bflo(u.z); a5 += bfhi(u.z); a6 += bflo(u.w); a7 += bfhi(u.w);
    }
    if (eo < hi - e) {   // 0..3 leftover edges
        int s = ssrc[e + eo];
        uint4 u = *(const uint4*)(h1s + (size_t)s * HID + g * 8);
        a0 += bflo(u.x); a1 += bfhi(u.x); a2 += bflo(u.y); a3 += bfhi(u.y);
        a4 += bflo(u.z); a5 += bfhi(u.z); a6 += bflo(u.w); a7 += bfhi(u.w);
    }

    a0 += __shfl_xor(a0, 16); a1 += __shfl_xor(a1, 16);
    a2 += __shfl_xor(a2, 16); a3 += __shfl_xor(a3, 16);
    a4 += __shfl_xor(a4, 16); a5 += __shfl_xor(a5, 16);
    a6 += __shfl_xor(a6, 16); a7 += __shfl_xor(a7, 16);
    a0 += __shfl_xor(a0, 32); a1 += __shfl_xor(a1, 32);
    a2 += __shfl_xor(a2, 32); a3 += __shfl_xor(a3, 32);
    a4 += __shfl_xor(a4, 32); a5 += __shfl_xor(a5, 32);
    a6 += __shfl_xor(a6, 32); a7 += __shfl_xor(a7, 32);

    float dd = dinv[node];
    if (eo == 0) {
        float4 bA = *(const float4*)(b1 + g * 8);
        float4 bB = *(const float4*)(b1 + g * 8 + 4);
        float* sr = srow[wave] + g * 8;
        sr[0] = fmaxf(fmaf(dd, a0, bA.x), 0.f);
        sr[1] = fmaxf(fmaf(dd, a1, bA.y), 0.f);
        sr[2] = fmaxf(fmaf(dd, a2, bA.z), 0.f);
        sr[3] = fmaxf(fmaf(dd, a3, bA.w), 0.f);
        sr[4] = fmaxf(fmaf(dd, a4, bB.x), 0.f);
        sr[5] = fmaxf(fmaf(dd, a5, bB.y), 0.f);
        sr[6] = fmaxf(fmaf(dd, a6, bB.z), 0.f);
        sr[7] = fmaxf(fmaf(dd, a7, bB.w), 0.f);
    }
    // same-wave LDS write->read: ordered, no barrier needed.
    // lane (eo,g): partial dot over k in [eo*32, eo*32+32) for output feature g.
    const float* sr = srow[wave];
    float p = 0.f;
#pragma unroll 8
    for (int kk = 0; kk < 32; ++kk) {
        int k = eo * 32 + kk;
        p = fmaf(sr[k], sw2[k * OUT_DIM + g], p);
    }
    p += __shfl_xor(p, 16);
    p += __shfl_xor(p, 32);
    if (eo == 0) h2s[(size_t)node * OUT_DIM + g] = p * dd;
}

// ================= layer-2 pull + fused bias + log_softmax =================
__global__ __launch_bounds__(256) void agg2_pull(const float* __restrict__ h2s,
                                                 const float* __restrict__ dinv,
                                                 const float* __restrict__ b2,
                                                 const int* __restrict__ rowptr,
                                                 const int* __restrict__ ssrc,
                                                 float* __restrict__ out) {
    int wave = threadIdx.x >> 6;
    int lane = threadIdx.x & 63;
    int node = __builtin_amdgcn_readfirstlane(blockIdx.x * 4 + wave);
    if (node >= N_NODES) return;
    int eo = lane >> 4;
    int f  = lane & 15;

    int lo = rowptr[node], hi = rowptr[node + 1];
    float acc = (eo == 0) ? h2s[(size_t)node * OUT_DIM + f] : 0.f;

    int e = lo;
#pragma unroll 2
    for (; e + 4 <= hi; e += 4)
        acc += h2s[(size_t)ssrc[e + eo] * OUT_DIM + f];
    if (e + eo < hi)
        acc += h2s[(size_t)ssrc[e + eo] * OUT_DIM + f];

    acc += __shfl_xor(acc, 16);
    acc += __shfl_xor(acc, 32);

    float dd = dinv[node];
    float v = fmaf(dd, acc, b2[f]);

    float m = v;
#pragma unroll
    for (int msk = 1; msk < 16; msk <<= 1) m = fmaxf(m, __shfl_xor(m, msk));
    float ex = __expf(v - m);
    float ssum = ex;
#pragma unroll
    for (int msk = 1; msk < 16; msk <<= 1) ssum += __shfl_xor(ssum, msk);
    if (eo == 0) out[(size_t)node * OUT_DIM + f] = v - m - __logf(ssum);
}

extern "C" void kernel_launch(void* const* d_in, const int* in_sizes, int n_in,
                              void* d_out, int out_size, void* d_ws, size_t ws_size,
                              hipStream_t stream) {
    const float* x  = (const float*)d_in[0];
    const int*   ei = (const int*)d_in[1];
    const float* W1 = (const float*)d_in[2];
    const float* b1 = (const float*)d_in[3];
    const float* W2 = (const float*)d_in[4];
    const float* b2 = (const float*)d_in[5];
    float* out = (float*)d_out;

    const int n = N_NODES;
    const int e = E_EDGES;
    const int* srcp = ei;        // edge_index[0]
    const int* dstp = ei + e;    // edge_index[1]

    // workspace layout
    char* w = (char*)d_ws;
    int*      cnt_bb = (int*)w;        w += (size_t)NBUCK * NBLK * 4;
    int*      btot   = (int*)w;        w += (size_t)NBUCK * 4;
    int*      bbase  = (int*)w;        w += (size_t)(NBUCK + 1) * 4;
    int*      rowptr = (int*)w;        w += (size_t)(n + 1) * 4;
    float*    dinv   = (float*)w;      w += (size_t)n * 4;
    unsigned* tmp    = (unsigned*)w;   w += (size_t)e * 4;
    int*      ssrc   = (int*)w;        w += (size_t)e * 4;
    uint4*    wtf    = (uint4*)w;      w += (size_t)64 * 64 * 16;   // frag-major bf16 W1
    short*    h1s    = (short*)w;      w += (size_t)n * HID * 2;    // bf16, pre-scaled
    float*    h2s    = (float*)w;      w += (size_t)n * OUT_DIM * 4;

    auto blk = [](long long total, int b) { return (int)((total + b - 1) / b); };

    // CSR build (bucketed counting sort; also produces rowptr + dinv);
    // W1 transpose piggybacks on the csr_b2 launch (independent blocks).
    csr_a<<<NBLK, 256, 0, stream>>>((const int4*)dstp, cnt_bb);
    csr_b1<<<NBUCK, NBLK, 0, stream>>>(cnt_bb, btot);
    csr_b2_w1t<<<9, 512, 0, stream>>>(btot, bbase, W1, wtf);
    csr_c<<<NBLK, 256, 0, stream>>>((const int4*)srcp, (const int4*)dstp, cnt_bb, bbase, tmp);
    csr_p2<<<NBUCK, 256, 0, stream>>>(tmp, bbase, rowptr, dinv, ssrc);

    // layer 1 GEMM + fused (aggregate1 + relu + layer-2 transform)
    gemm1_mfma<<<blk(n, 128), 512, 0, stream>>>(x, wtf, dinv, h1s);
    agg1_fused<<<blk(n, 4), 256, 0, stream>>>(h1s, dinv, b1, W2, rowptr, ssrc, h2s);

    // layer 2 aggregate + log_softmax
    agg2_pull<<<blk(n, 4), 256, 0, stream>>>(h2s, dinv, b2, rowptr, ssrc, out);
}

// Round 9
// 195.472 us; speedup vs baseline: 4.8366x; 1.0202x over previous
//
#include <hip/hip_runtime.h>
#include <hip/hip_bf16.h>

#define N_NODES 50000
#define E_EDGES 800000
#define IN_DIM  256
#define HID     128
#define OUT_DIM 16

#define NBUCK 391    // ceil(50000/128) buckets of 128 nodes (dst>>7)
#define NBLK  128    // blocks for bucket phases A/C
#define P2CAP 4096   // max edges per bucket (mean 2046, sigma ~45)

using frag_ab = __attribute__((ext_vector_type(8))) short;  // 8 bf16
using frag_cd = __attribute__((ext_vector_type(4))) float;  // 4 fp32

static __device__ inline short f2bf(float f) {
    union { float f; unsigned u; } v; v.f = f;
    unsigned r = (v.u + 0x7fffu + ((v.u >> 16) & 1u)) >> 16;
    return (short)r;
}
static __device__ inline float bflo(unsigned u) {
    union { unsigned u; float f; } v; v.u = u << 16; return v.f;
}
static __device__ inline float bfhi(unsigned u) {
    union { unsigned u; float f; } v; v.u = u & 0xffff0000u; return v.f;
}
static __device__ inline unsigned packbf(float a, float b) {
    return (unsigned)(unsigned short)f2bf(a) | ((unsigned)(unsigned short)f2bf(b) << 16);
}

// ================= CSR build: 2-level bucketed counting sort =================

__global__ __launch_bounds__(256) void csr_a(const int4* __restrict__ dst4,
                                             int* __restrict__ cnt_bb) {
    __shared__ int h[NBUCK];
    int t = threadIdx.x;
    for (int i = t; i < NBUCK; i += 256) h[i] = 0;
    __syncthreads();
    for (int i = blockIdx.x * 256 + t; i < E_EDGES / 4; i += NBLK * 256) {
        int4 d = dst4[i];
        atomicAdd(&h[d.x >> 7], 1);
        atomicAdd(&h[d.y >> 7], 1);
        atomicAdd(&h[d.z >> 7], 1);
        atomicAdd(&h[d.w >> 7], 1);
    }
    __syncthreads();
    for (int i = t; i < NBUCK; i += 256) cnt_bb[i * NBLK + blockIdx.x] = h[i];
}

__global__ __launch_bounds__(NBLK) void csr_b1(int* __restrict__ cnt_bb,
                                               int* __restrict__ btot) {
    __shared__ int sm[NBLK];
    int b = blockIdx.x, t = threadIdx.x;
    int v = cnt_bb[b * NBLK + t];
    sm[t] = v;
    __syncthreads();
    for (int o = 1; o < NBLK; o <<= 1) {
        int u = (t >= o) ? sm[t - o] : 0;
        __syncthreads();
        sm[t] += u;
        __syncthreads();
    }
    cnt_bb[b * NBLK + t] = sm[t] - v;
    if (t == NBLK - 1) btot[b] = sm[t];
}

// blocks 0..7: W1 -> fragment-major bf16 transpose; block 8: scan of btot.
__global__ __launch_bounds__(512) void csr_b2_w1t(const int* __restrict__ btot,
                                                  int* __restrict__ bbase,
                                                  const float* __restrict__ W,
                                                  uint4* __restrict__ wtf) {
    int t = threadIdx.x;
    if (blockIdx.x < 8) {
        int j = blockIdx.x * 512 + t;
        int f = j >> 6, lane = j & 63;
        int kt = f >> 3, tt = f & 7;
        int m = lane & 15, q = lane >> 4;
        int c = tt * 16 + m;
        int k0 = kt * 32 + q * 8;
        unsigned p[4];
#pragma unroll
        for (int i = 0; i < 4; ++i)
            p[i] = packbf(W[(k0 + 2 * i) * HID + c], W[(k0 + 2 * i + 1) * HID + c]);
        uint4 v; v.x = p[0]; v.y = p[1]; v.z = p[2]; v.w = p[3];
        wtf[j] = v;
        return;
    }
    __shared__ int sm[512];
    int v = (t < NBUCK) ? btot[t] : 0;
    sm[t] = v;
    __syncthreads();
    for (int o = 1; o < 512; o <<= 1) {
        int u = (t >= o) ? sm[t - o] : 0;
        __syncthreads();
        sm[t] += u;
        __syncthreads();
    }
    if (t < NBUCK) bbase[t] = sm[t] - v;
    if (t == 511) bbase[NBUCK] = sm[511];
}

__global__ __launch_bounds__(256) void csr_c(const int4* __restrict__ src4,
                                             const int4* __restrict__ dst4,
                                             const int* __restrict__ cnt_bb,
                                             const int* __restrict__ bbase,
                                             unsigned* __restrict__ tmp) {
    __shared__ int run[NBUCK];
    int t = threadIdx.x;
    for (int i = t; i < NBUCK; i += 256)
        run[i] = bbase[i] + cnt_bb[i * NBLK + blockIdx.x];
    __syncthreads();
    for (int i = blockIdx.x * 256 + t; i < E_EDGES / 4; i += NBLK * 256) {
        int4 d = dst4[i];
        int4 s = src4[i];
        int p0 = atomicAdd(&run[d.x >> 7], 1);
        tmp[p0] = (unsigned)s.x | ((unsigned)(d.x & 127) << 17);
        int p1 = atomicAdd(&run[d.y >> 7], 1);
        tmp[p1] = (unsigned)s.y | ((unsigned)(d.y & 127) << 17);
        int p2 = atomicAdd(&run[d.z >> 7], 1);
        tmp[p2] = (unsigned)s.z | ((unsigned)(d.z & 127) << 17);
        int p3 = atomicAdd(&run[d.w >> 7], 1);
        tmp[p3] = (unsigned)s.w | ((unsigned)(d.w & 127) << 17);
    }
}

__global__ __launch_bounds__(256) void csr_p2(const unsigned* __restrict__ tmp,
                                              const int* __restrict__ bbase,
                                              int* __restrict__ rowptr,
                                              float* __restrict__ dinv,
                                              int* __restrict__ ssrc) {
    __shared__ unsigned ed[P2CAP];
    __shared__ int cnt[128];
    __shared__ int off[128];
    int b = blockIdx.x, t = threadIdx.x;
    int base = bbase[b];
    int m = bbase[b + 1] - base;
    if (m > P2CAP) m = P2CAP;
    if (t < 128) cnt[t] = 0;
    __syncthreads();
    for (int i = t; i < m; i += 256) {
        unsigned v = tmp[base + i];
        ed[i] = v;
        atomicAdd(&cnt[v >> 17], 1);
    }
    __syncthreads();
    if (t < 128) off[t] = cnt[t];
    __syncthreads();
    for (int o = 1; o < 128; o <<= 1) {
        int u = (t >= o && t < 128) ? off[t - o] : 0;
        __syncthreads();
        if (t < 128) off[t] += u;
        __syncthreads();
    }
    if (t < 128) {
        int node = b * 128 + t;
        int ex = off[t] - cnt[t];
        if (node < N_NODES) {
            rowptr[node] = base + ex;
            dinv[node] = rsqrtf((float)(cnt[t] + 1));
        }
        off[t] = ex;
    }
    if (b == NBUCK - 1 && t == 0) rowptr[N_NODES] = E_EDGES;
    __syncthreads();
    for (int i = t; i < m; i += 256) {
        unsigned v = ed[i];
        int p = atomicAdd(&off[v >> 17], 1);
        ssrc[base + p] = (int)(v & 0x1FFFF);
    }
}

// ================= layer-1 GEMM: LDS-staged B, bf16 MFMA ====================
__global__ __launch_bounds__(512) void gemm1_mfma(const float* __restrict__ x,
                                                  const uint4* __restrict__ wtf,
                                                  const float* __restrict__ dinv,
                                                  short* __restrict__ h) {
    __shared__ uint4 lwt[64 * 64];   // 64 KB
    int tid = threadIdx.x;
#pragma unroll
    for (int i = 0; i < 8; ++i)
        lwt[i * 512 + tid] = wtf[i * 512 + tid];

    int wave = tid >> 6;
    int lane = tid & 63;
    int m = lane & 15;
    int q = lane >> 4;
    int row0 = blockIdx.x * 128 + wave * 16;
    int arow_idx = row0 + m;
    const float4* arow4 = (const float4*)(x + (size_t)(arow_idx < N_NODES ? arow_idx : 0) * IN_DIM);

    frag_ab a[8];
#pragma unroll
    for (int kt = 0; kt < 8; ++kt) {
        float4 f0 = arow4[kt * 8 + q * 2];
        float4 f1 = arow4[kt * 8 + q * 2 + 1];
        a[kt][0] = f2bf(f0.x); a[kt][1] = f2bf(f0.y); a[kt][2] = f2bf(f0.z); a[kt][3] = f2bf(f0.w);
        a[kt][4] = f2bf(f1.x); a[kt][5] = f2bf(f1.y); a[kt][6] = f2bf(f1.z); a[kt][7] = f2bf(f1.w);
    }

    frag_cd acc[8];
#pragma unroll
    for (int t = 0; t < 8; ++t) acc[t] = frag_cd{0.f, 0.f, 0.f, 0.f};

    __syncthreads();

#pragma unroll
    for (int kt = 0; kt < 8; ++kt) {
#pragma unroll
        for (int t = 0; t < 8; ++t) {
            frag_ab b = *(const frag_ab*)&lwt[(kt * 8 + t) * 64 + lane];
            acc[t] = __builtin_amdgcn_mfma_f32_16x16x32_bf16(a[kt], b, acc[t], 0, 0, 0);
        }
    }

    float dv[4];
#pragma unroll
    for (int r = 0; r < 4; ++r) {
        int orow = row0 + q * 4 + r;
        dv[r] = (orow < N_NODES) ? dinv[orow] : 0.f;
    }
#pragma unroll
    for (int t = 0; t < 8; ++t) {
#pragma unroll
        for (int r = 0; r < 4; ++r) {
            int orow = row0 + q * 4 + r;
            if (orow < N_NODES)
                h[(size_t)orow * HID + t * 16 + m] = f2bf(acc[t][r] * dv[r]);
        }
    }
}

// ===== layer-1 pull + fused layer-2 transform ===============================
// 8 edges in flight per iter; W2 dot uses k = eo + 4*kk interleave:
//   srow banks (eo+4kk)%32 -> 4 distinct banks, broadcast across g (0-way)
//   sw2  banks (eo*16+g)%32 -> exactly 2 lanes/bank (free per m136)
// h2s written as packed bf16 (dword = 2 features).
__global__ __launch_bounds__(256) void agg1_fused(const short* __restrict__ h1s,
                                                  const float* __restrict__ dinv,
                                                  const float* __restrict__ b1,
                                                  const float* __restrict__ W2,
                                                  const int* __restrict__ rowptr,
                                                  const int* __restrict__ ssrc,
                                                  unsigned* __restrict__ h2s) {
    __shared__ float sw2[HID * OUT_DIM];   // 8 KB, [k][f]
    __shared__ float srow[4][HID];         // 2 KB
    int tid = threadIdx.x;
#pragma unroll
    for (int i = 0; i < 8; ++i) sw2[i * 256 + tid] = W2[i * 256 + tid];
    __syncthreads();

    int wave = tid >> 6;
    int lane = tid & 63;
    int node = __builtin_amdgcn_readfirstlane(blockIdx.x * 4 + wave);
    if (node >= N_NODES) return;
    int eo = lane >> 4;       // edge slot in quad
    int g  = lane & 15;       // feature octet

    int lo = rowptr[node], hi = rowptr[node + 1];
    float a0 = 0.f, a1 = 0.f, a2 = 0.f, a3 = 0.f;
    float a4 = 0.f, a5 = 0.f, a6 = 0.f, a7 = 0.f;

    if (eo == 0) {   // self-loop row
        uint4 u = *(const uint4*)(h1s + (size_t)node * HID + g * 8);
        a0 = bflo(u.x); a1 = bfhi(u.x); a2 = bflo(u.y); a3 = bfhi(u.y);
        a4 = bflo(u.z); a5 = bfhi(u.z); a6 = bflo(u.w); a7 = bfhi(u.w);
    }

    int e = lo;
    for (; e + 8 <= hi; e += 8) {   // 8 gathers in flight across the wave
        int s0 = ssrc[e + eo];
        int s1 = ssrc[e + 4 + eo];
        uint4 u0 = *(const uint4*)(h1s + (size_t)s0 * HID + g * 8);
        uint4 u1 = *(const uint4*)(h1s + (size_t)s1 * HID + g * 8);
        a0 += bflo(u0.x); a1 += bfhi(u0.x); a2 += bflo(u0.y); a3 += bfhi(u0.y);
        a4 += bflo(u0.z); a5 += bfhi(u0.z); a6 += bflo(u0.w); a7 += bfhi(u0.w);
        a0 += bflo(u1.x); a1 += bfhi(u1.x); a2 += bflo(u1.y); a3 += bfhi(u1.y);
        a4 += bflo(u1.z); a5 += bfhi(u1.z); a6 += bflo(u1.w); a7 += bfhi(u1.w);
    }
    int rem = hi - e;
    if (eo < rem) {
        int s = ssrc[e + eo];
        uint4 u = *(const uint4*)(h1s + (size_t)s * HID + g * 8);
        a0 += bflo(u.x); a1 += bfhi(u.x); a2 += bflo(u.y); a3 += bfhi(u.y);
        a4 += bflo(u.z); a5 += bfhi(u.z); a6 += bflo(u.w); a7 += bfhi(u.w);
    }
    if (eo + 4 < rem) {
        int s = ssrc[e + 4 + eo];
        uint4 u = *(const uint4*)(h1s + (size_t)s * HID + g * 8);
        a0 += bflo(u.x); a1 += bfhi(u.x); a2 += bflo(u.y); a3 += bfhi(u.y);
        a4 += bflo(u.z); a5 += bfhi(u.z); a6 += bflo(u.w); a7 += bfhi(u.w);
    }

    a0 += __shfl_xor(a0, 16); a1 += __shfl_xor(a1, 16);
    a2 += __shfl_xor(a2, 16); a3 += __shfl_xor(a3, 16);
    a4 += __shfl_xor(a4, 16); a5 += __shfl_xor(a5, 16);
    a6 += __shfl_xor(a6, 16); a7 += __shfl_xor(a7, 16);
    a0 += __shfl_xor(a0, 32); a1 += __shfl_xor(a1, 32);
    a2 += __shfl_xor(a2, 32); a3 += __shfl_xor(a3, 32);
    a4 += __shfl_xor(a4, 32); a5 += __shfl_xor(a5, 32);
    a6 += __shfl_xor(a6, 32); a7 += __shfl_xor(a7, 32);

    float dd = dinv[node];
    if (eo == 0) {
        float4 bA = *(const float4*)(b1 + g * 8);
        float4 bB = *(const float4*)(b1 + g * 8 + 4);
        float* sr = srow[wave] + g * 8;
        sr[0] = fmaxf(fmaf(dd, a0, bA.x), 0.f);
        sr[1] = fmaxf(fmaf(dd, a1, bA.y), 0.f);
        sr[2] = fmaxf(fmaf(dd, a2, bA.z), 0.f);
        sr[3] = fmaxf(fmaf(dd, a3, bA.w), 0.f);
        sr[4] = fmaxf(fmaf(dd, a4, bB.x), 0.f);
        sr[5] = fmaxf(fmaf(dd, a5, bB.y), 0.f);
        sr[6] = fmaxf(fmaf(dd, a6, bB.z), 0.f);
        sr[7] = fmaxf(fmaf(dd, a7, bB.w), 0.f);
    }
    // same-wave LDS write->read: ordered, no barrier needed.
    // lane (eo,g): output feature g, k in {eo, eo+4, ..., eo+124}.
    const float* sr = srow[wave];
    float p = 0.f;
#pragma unroll 8
    for (int kk = 0; kk < 32; ++kk) {
        int k = eo + 4 * kk;
        p = fmaf(sr[k], sw2[k * OUT_DIM + g], p);
    }
    p += __shfl_xor(p, 16);
    p += __shfl_xor(p, 32);
    p *= dd;
    float pn = __shfl_xor(p, 1);   // feature g^1's value
    if (eo == 0 && (g & 1) == 0)
        h2s[(size_t)node * 8 + (g >> 1)] = packbf(p, pn);
}

// ===== layer-2 pull (bf16 rows, 8 edges/iter) + bias + log_softmax =========
// lane = eo*8 + g; eo in [0,8) edge slot, g in [0,8) feature pair (dword).
__global__ __launch_bounds__(256) void agg2_pull(const unsigned* __restrict__ h2s,
                                                 const float* __restrict__ dinv,
                                                 const float* __restrict__ b2,
                                                 const int* __restrict__ rowptr,
                                                 const int* __restrict__ ssrc,
                                                 float* __restrict__ out) {
    int wave = threadIdx.x >> 6;
    int lane = threadIdx.x & 63;
    int node = __builtin_amdgcn_readfirstlane(blockIdx.x * 4 + wave);
    if (node >= N_NODES) return;
    int eo = lane >> 3;
    int g  = lane & 7;

    int lo = rowptr[node], hi = rowptr[node + 1];
    float a0 = 0.f, a1 = 0.f;
    if (eo == 0) {
        unsigned u = h2s[(size_t)node * 8 + g];
        a0 = bflo(u); a1 = bfhi(u);
    }
    int e = lo;
    for (; e + 8 <= hi; e += 8) {
        int s = ssrc[e + eo];
        unsigned u = h2s[(size_t)s * 8 + g];
        a0 += bflo(u); a1 += bfhi(u);
    }
    if (eo < hi - e) {
        int s = ssrc[e + eo];
        unsigned u = h2s[(size_t)s * 8 + g];
        a0 += bflo(u); a1 += bfhi(u);
    }

    a0 += __shfl_xor(a0, 8);  a1 += __shfl_xor(a1, 8);
    a0 += __shfl_xor(a0, 16); a1 += __shfl_xor(a1, 16);
    a0 += __shfl_xor(a0, 32); a1 += __shfl_xor(a1, 32);

    float dd = dinv[node];
    float2 bb = *(const float2*)(b2 + 2 * g);
    float v0 = fmaf(dd, a0, bb.x);
    float v1 = fmaf(dd, a1, bb.y);

    float m = fmaxf(v0, v1);
#pragma unroll
    for (int msk = 1; msk < 8; msk <<= 1) m = fmaxf(m, __shfl_xor(m, msk));
    float s2 = __expf(v0 - m) + __expf(v1 - m);
#pragma unroll
    for (int msk = 1; msk < 8; msk <<= 1) s2 += __shfl_xor(s2, msk);
    float lse = m + __logf(s2);
    if (eo == 0) {
        float2 o; o.x = v0 - lse; o.y = v1 - lse;
        *(float2*)(out + (size_t)node * OUT_DIM + 2 * g) = o;
    }
}

extern "C" void kernel_launch(void* const* d_in, const int* in_sizes, int n_in,
                              void* d_out, int out_size, void* d_ws, size_t ws_size,
                              hipStream_t stream) {
    const float* x  = (const float*)d_in[0];
    const int*   ei = (const int*)d_in[1];
    const float* W1 = (const float*)d_in[2];
    const float* b1 = (const float*)d_in[3];
    const float* W2 = (const float*)d_in[4];
    const float* b2 = (const float*)d_in[5];
    float* out = (float*)d_out;

    const int n = N_NODES;
    const int e = E_EDGES;
    const int* srcp = ei;        // edge_index[0]
    const int* dstp = ei + e;    // edge_index[1]

    // workspace layout
    char* w = (char*)d_ws;
    int*      cnt_bb = (int*)w;        w += (size_t)NBUCK * NBLK * 4;
    int*      btot   = (int*)w;        w += (size_t)NBUCK * 4;
    int*      bbase  = (int*)w;        w += (size_t)(NBUCK + 1) * 4;
    int*      rowptr = (int*)w;        w += (size_t)(n + 1) * 4;
    float*    dinv   = (float*)w;      w += (size_t)n * 4;
    unsigned* tmp    = (unsigned*)w;   w += (size_t)e * 4;
    int*      ssrc   = (int*)w;        w += (size_t)e * 4;
    uint4*    wtf    = (uint4*)w;      w += (size_t)64 * 64 * 16;   // frag-major bf16 W1
    short*    h1s    = (short*)w;      w += (size_t)n * HID * 2;    // bf16, pre-scaled
    unsigned* h2s    = (unsigned*)w;   w += (size_t)n * 8 * 4;      // bf16 packed, 8 dw/node

    auto blk = [](long long total, int b) { return (int)((total + b - 1) / b); };

    // CSR build (bucketed counting sort; also produces rowptr + dinv);
    // W1 transpose piggybacks on the csr_b2 launch (independent blocks).
    csr_a<<<NBLK, 256, 0, stream>>>((const int4*)dstp, cnt_bb);
    csr_b1<<<NBUCK, NBLK, 0, stream>>>(cnt_bb, btot);
    csr_b2_w1t<<<9, 512, 0, stream>>>(btot, bbase, W1, wtf);
    csr_c<<<NBLK, 256, 0, stream>>>((const int4*)srcp, (const int4*)dstp, cnt_bb, bbase, tmp);
    csr_p2<<<NBUCK, 256, 0, stream>>>(tmp, bbase, rowptr, dinv, ssrc);

    // layer 1 GEMM + fused (aggregate1 + relu + layer-2 transform)
    gemm1_mfma<<<blk(n, 128), 512, 0, stream>>>(x, wtf, dinv, h1s);
    agg1_fused<<<blk(n, 4), 256, 0, stream>>>(h1s, dinv, b1, W2, rowptr, ssrc, h2s);

    // layer 2 aggregate + log_softmax
    agg2_pull<<<blk(n, 4), 256, 0, stream>>>(h2s, dinv, b2, rowptr, ssrc, out);
}

// Round 10
// 193.388 us; speedup vs baseline: 4.8887x; 1.0108x over previous
//
#include <hip/hip_runtime.h>
#include <hip/hip_bf16.h>

#define N_NODES 50000
#define E_EDGES 800000
#define IN_DIM  256
#define HID     128
#define OUT_DIM 16

#define NBUCK 391    // ceil(50000/128) buckets of 128 nodes (dst>>7)
#define NBLK  128    // blocks for bucket phases A/C
#define P2CAP 4096   // max edges per bucket (mean 2046, sigma ~45)

using frag_ab = __attribute__((ext_vector_type(8))) short;  // 8 bf16
using frag_cd = __attribute__((ext_vector_type(4))) float;  // 4 fp32

static __device__ inline short f2bf(float f) {
    union { float f; unsigned u; } v; v.f = f;
    unsigned r = (v.u + 0x7fffu + ((v.u >> 16) & 1u)) >> 16;
    return (short)r;
}
static __device__ inline float bflo(unsigned u) {
    union { unsigned u; float f; } v; v.u = u << 16; return v.f;
}
static __device__ inline float bfhi(unsigned u) {
    union { unsigned u; float f; } v; v.u = u & 0xffff0000u; return v.f;
}
static __device__ inline unsigned packbf(float a, float b) {
    return (unsigned)(unsigned short)f2bf(a) | ((unsigned)(unsigned short)f2bf(b) << 16);
}

// ================= CSR build: 2-level bucketed counting sort =================

__global__ __launch_bounds__(256) void csr_a(const int4* __restrict__ dst4,
                                             int* __restrict__ cnt_bb) {
    __shared__ int h[NBUCK];
    int t = threadIdx.x;
    for (int i = t; i < NBUCK; i += 256) h[i] = 0;
    __syncthreads();
    for (int i = blockIdx.x * 256 + t; i < E_EDGES / 4; i += NBLK * 256) {
        int4 d = dst4[i];
        atomicAdd(&h[d.x >> 7], 1);
        atomicAdd(&h[d.y >> 7], 1);
        atomicAdd(&h[d.z >> 7], 1);
        atomicAdd(&h[d.w >> 7], 1);
    }
    __syncthreads();
    for (int i = t; i < NBUCK; i += 256) cnt_bb[i * NBLK + blockIdx.x] = h[i];
}

__global__ __launch_bounds__(NBLK) void csr_b1(int* __restrict__ cnt_bb,
                                               int* __restrict__ btot) {
    __shared__ int sm[NBLK];
    int b = blockIdx.x, t = threadIdx.x;
    int v = cnt_bb[b * NBLK + t];
    sm[t] = v;
    __syncthreads();
    for (int o = 1; o < NBLK; o <<= 1) {
        int u = (t >= o) ? sm[t - o] : 0;
        __syncthreads();
        sm[t] += u;
        __syncthreads();
    }
    cnt_bb[b * NBLK + t] = sm[t] - v;
    if (t == NBLK - 1) btot[b] = sm[t];
}

// blocks 0..7: W1 -> fragment-major bf16 transpose; block 8: scan of btot.
__global__ __launch_bounds__(512) void csr_b2_w1t(const int* __restrict__ btot,
                                                  int* __restrict__ bbase,
                                                  const float* __restrict__ W,
                                                  uint4* __restrict__ wtf) {
    int t = threadIdx.x;
    if (blockIdx.x < 8) {
        int j = blockIdx.x * 512 + t;
        int f = j >> 6, lane = j & 63;
        int kt = f >> 3, tt = f & 7;
        int m = lane & 15, q = lane >> 4;
        int c = tt * 16 + m;
        int k0 = kt * 32 + q * 8;
        unsigned p[4];
#pragma unroll
        for (int i = 0; i < 4; ++i)
            p[i] = packbf(W[(k0 + 2 * i) * HID + c], W[(k0 + 2 * i + 1) * HID + c]);
        uint4 v; v.x = p[0]; v.y = p[1]; v.z = p[2]; v.w = p[3];
        wtf[j] = v;
        return;
    }
    __shared__ int sm[512];
    int v = (t < NBUCK) ? btot[t] : 0;
    sm[t] = v;
    __syncthreads();
    for (int o = 1; o < 512; o <<= 1) {
        int u = (t >= o) ? sm[t - o] : 0;
        __syncthreads();
        sm[t] += u;
        __syncthreads();
    }
    if (t < NBUCK) bbase[t] = sm[t] - v;
    if (t == 511) bbase[NBUCK] = sm[511];
}

__global__ __launch_bounds__(256) void csr_c(const int4* __restrict__ src4,
                                             const int4* __restrict__ dst4,
                                             const int* __restrict__ cnt_bb,
                                             const int* __restrict__ bbase,
                                             unsigned* __restrict__ tmp) {
    __shared__ int run[NBUCK];
    int t = threadIdx.x;
    for (int i = t; i < NBUCK; i += 256)
        run[i] = bbase[i] + cnt_bb[i * NBLK + blockIdx.x];
    __syncthreads();
    for (int i = blockIdx.x * 256 + t; i < E_EDGES / 4; i += NBLK * 256) {
        int4 d = dst4[i];
        int4 s = src4[i];
        int p0 = atomicAdd(&run[d.x >> 7], 1);
        tmp[p0] = (unsigned)s.x | ((unsigned)(d.x & 127) << 17);
        int p1 = atomicAdd(&run[d.y >> 7], 1);
        tmp[p1] = (unsigned)s.y | ((unsigned)(d.y & 127) << 17);
        int p2 = atomicAdd(&run[d.z >> 7], 1);
        tmp[p2] = (unsigned)s.z | ((unsigned)(d.z & 127) << 17);
        int p3 = atomicAdd(&run[d.w >> 7], 1);
        tmp[p3] = (unsigned)s.w | ((unsigned)(d.w & 127) << 17);
    }
}

__global__ __launch_bounds__(256) void csr_p2(const unsigned* __restrict__ tmp,
                                              const int* __restrict__ bbase,
                                              int* __restrict__ rowptr,
                                              float* __restrict__ dinv,
                                              int* __restrict__ ssrc) {
    __shared__ unsigned ed[P2CAP];
    __shared__ int cnt[128];
    __shared__ int off[128];
    int b = blockIdx.x, t = threadIdx.x;
    int base = bbase[b];
    int m = bbase[b + 1] - base;
    if (m > P2CAP) m = P2CAP;
    if (t < 128) cnt[t] = 0;
    __syncthreads();
    for (int i = t; i < m; i += 256) {
        unsigned v = tmp[base + i];
        ed[i] = v;
        atomicAdd(&cnt[v >> 17], 1);
    }
    __syncthreads();
    if (t < 128) off[t] = cnt[t];
    __syncthreads();
    for (int o = 1; o < 128; o <<= 1) {
        int u = (t >= o && t < 128) ? off[t - o] : 0;
        __syncthreads();
        if (t < 128) off[t] += u;
        __syncthreads();
    }
    if (t < 128) {
        int node = b * 128 + t;
        int ex = off[t] - cnt[t];
        if (node < N_NODES) {
            rowptr[node] = base + ex;
            dinv[node] = rsqrtf((float)(cnt[t] + 1));
        }
        off[t] = ex;
    }
    if (b == NBUCK - 1 && t == 0) rowptr[N_NODES] = E_EDGES;
    __syncthreads();
    for (int i = t; i < m; i += 256) {
        unsigned v = ed[i];
        int p = atomicAdd(&off[v >> 17], 1);
        ssrc[base + p] = (int)(v & 0x1FFFF);
    }
}

// ================= layer-1 GEMM: LDS-staged B, bf16 MFMA ====================
__global__ __launch_bounds__(512) void gemm1_mfma(const float* __restrict__ x,
                                                  const uint4* __restrict__ wtf,
                                                  const float* __restrict__ dinv,
                                                  short* __restrict__ h) {
    __shared__ uint4 lwt[64 * 64];   // 64 KB
    int tid = threadIdx.x;
#pragma unroll
    for (int i = 0; i < 8; ++i)
        lwt[i * 512 + tid] = wtf[i * 512 + tid];

    int wave = tid >> 6;
    int lane = tid & 63;
    int m = lane & 15;
    int q = lane >> 4;
    int row0 = blockIdx.x * 128 + wave * 16;
    int arow_idx = row0 + m;
    const float4* arow4 = (const float4*)(x + (size_t)(arow_idx < N_NODES ? arow_idx : 0) * IN_DIM);

    frag_ab a[8];
#pragma unroll
    for (int kt = 0; kt < 8; ++kt) {
        float4 f0 = arow4[kt * 8 + q * 2];
        float4 f1 = arow4[kt * 8 + q * 2 + 1];
        a[kt][0] = f2bf(f0.x); a[kt][1] = f2bf(f0.y); a[kt][2] = f2bf(f0.z); a[kt][3] = f2bf(f0.w);
        a[kt][4] = f2bf(f1.x); a[kt][5] = f2bf(f1.y); a[kt][6] = f2bf(f1.z); a[kt][7] = f2bf(f1.w);
    }

    frag_cd acc[8];
#pragma unroll
    for (int t = 0; t < 8; ++t) acc[t] = frag_cd{0.f, 0.f, 0.f, 0.f};

    __syncthreads();

#pragma unroll
    for (int kt = 0; kt < 8; ++kt) {
#pragma unroll
        for (int t = 0; t < 8; ++t) {
            frag_ab b = *(const frag_ab*)&lwt[(kt * 8 + t) * 64 + lane];
            acc[t] = __builtin_amdgcn_mfma_f32_16x16x32_bf16(a[kt], b, acc[t], 0, 0, 0);
        }
    }

    float dv[4];
#pragma unroll
    for (int r = 0; r < 4; ++r) {
        int orow = row0 + q * 4 + r;
        dv[r] = (orow < N_NODES) ? dinv[orow] : 0.f;
    }
#pragma unroll
    for (int t = 0; t < 8; ++t) {
#pragma unroll
        for (int r = 0; r < 4; ++r) {
            int orow = row0 + q * 4 + r;
            if (orow < N_NODES)
                h[(size_t)orow * HID + t * 16 + m] = f2bf(acc[t][r] * dv[r]);
        }
    }
}

// ===== layer-1 pull + fused layer-2 transform ===============================
// 16 edges/iter: 4 independent broadcast ssrc loads + 4 independent uint4
// gathers held live simultaneously (forces MLP; VGPR target ~48).
__global__ __launch_bounds__(256) void agg1_fused(const short* __restrict__ h1s,
                                                  const float* __restrict__ dinv,
                                                  const float* __restrict__ b1,
                                                  const float* __restrict__ W2,
                                                  const int* __restrict__ rowptr,
                                                  const int* __restrict__ ssrc,
                                                  unsigned* __restrict__ h2s) {
    __shared__ float sw2[HID * OUT_DIM];   // 8 KB, [k][f]
    __shared__ float srow[4][HID];         // 2 KB
    int tid = threadIdx.x;
#pragma unroll
    for (int i = 0; i < 8; ++i) sw2[i * 256 + tid] = W2[i * 256 + tid];
    __syncthreads();

    int wave = tid >> 6;
    int lane = tid & 63;
    int node = __builtin_amdgcn_readfirstlane(blockIdx.x * 4 + wave);
    if (node >= N_NODES) return;
    int eo = lane >> 4;       // edge slot in quad
    int g  = lane & 15;       // feature octet

    int lo = rowptr[node], hi = rowptr[node + 1];
    float a0 = 0.f, a1 = 0.f, a2 = 0.f, a3 = 0.f;
    float a4 = 0.f, a5 = 0.f, a6 = 0.f, a7 = 0.f;

    if (eo == 0) {   // self-loop row
        uint4 u = *(const uint4*)(h1s + (size_t)node * HID + g * 8);
        a0 = bflo(u.x); a1 = bfhi(u.x); a2 = bflo(u.y); a3 = bfhi(u.y);
        a4 = bflo(u.z); a5 = bfhi(u.z); a6 = bflo(u.w); a7 = bfhi(u.w);
    }

    int e = lo;
    for (; e + 16 <= hi; e += 16) {
        // 4 independent index loads, then 4 independent row gathers — all
        // outstanding together before any accumulate.
        int s0 = ssrc[e + eo];
        int s1 = ssrc[e + 4 + eo];
        int s2 = ssrc[e + 8 + eo];
        int s3 = ssrc[e + 12 + eo];
        uint4 u0 = *(const uint4*)(h1s + (size_t)s0 * HID + g * 8);
        uint4 u1 = *(const uint4*)(h1s + (size_t)s1 * HID + g * 8);
        uint4 u2 = *(const uint4*)(h1s + (size_t)s2 * HID + g * 8);
        uint4 u3 = *(const uint4*)(h1s + (size_t)s3 * HID + g * 8);
        a0 += bflo(u0.x); a1 += bfhi(u0.x); a2 += bflo(u0.y); a3 += bfhi(u0.y);
        a4 += bflo(u0.z); a5 += bfhi(u0.z); a6 += bflo(u0.w); a7 += bfhi(u0.w);
        a0 += bflo(u1.x); a1 += bfhi(u1.x); a2 += bflo(u1.y); a3 += bfhi(u1.y);
        a4 += bflo(u1.z); a5 += bfhi(u1.z); a6 += bflo(u1.w); a7 += bfhi(u1.w);
        a0 += bflo(u2.x); a1 += bfhi(u2.x); a2 += bflo(u2.y); a3 += bfhi(u2.y);
        a4 += bflo(u2.z); a5 += bfhi(u2.z); a6 += bflo(u2.w); a7 += bfhi(u2.w);
        a0 += bflo(u3.x); a1 += bfhi(u3.x); a2 += bflo(u3.y); a3 += bfhi(u3.y);
        a4 += bflo(u3.z); a5 += bfhi(u3.z); a6 += bflo(u3.w); a7 += bfhi(u3.w);
    }
    for (; e + 4 <= hi; e += 4) {
        int s = ssrc[e + eo];
        uint4 u = *(const uint4*)(h1s + (size_t)s * HID + g * 8);
        a0 += bflo(u.x); a1 += bfhi(u.x); a2 += bflo(u.y); a3 += bfhi(u.y);
        a4 += bflo(u.z); a5 += bfhi(u.z); a6 += bflo(u.w); a7 += bfhi(u.w);
    }
    if (eo < hi - e) {
        int s = ssrc[e + eo];
        uint4 u = *(const uint4*)(h1s + (size_t)s * HID + g * 8);
        a0 += bflo(u.x); a1 += bfhi(u.x); a2 += bflo(u.y); a3 += bfhi(u.y);
        a4 += bflo(u.z); a5 += bfhi(u.z); a6 += bflo(u.w); a7 += bfhi(u.w);
    }

    a0 += __shfl_xor(a0, 16); a1 += __shfl_xor(a1, 16);
    a2 += __shfl_xor(a2, 16); a3 += __shfl_xor(a3, 16);
    a4 += __shfl_xor(a4, 16); a5 += __shfl_xor(a5, 16);
    a6 += __shfl_xor(a6, 16); a7 += __shfl_xor(a7, 16);
    a0 += __shfl_xor(a0, 32); a1 += __shfl_xor(a1, 32);
    a2 += __shfl_xor(a2, 32); a3 += __shfl_xor(a3, 32);
    a4 += __shfl_xor(a4, 32); a5 += __shfl_xor(a5, 32);
    a6 += __shfl_xor(a6, 32); a7 += __shfl_xor(a7, 32);

    float dd = dinv[node];
    if (eo == 0) {
        float4 bA = *(const float4*)(b1 + g * 8);
        float4 bB = *(const float4*)(b1 + g * 8 + 4);
        float* sr = srow[wave] + g * 8;
        sr[0] = fmaxf(fmaf(dd, a0, bA.x), 0.f);
        sr[1] = fmaxf(fmaf(dd, a1, bA.y), 0.f);
        sr[2] = fmaxf(fmaf(dd, a2, bA.z), 0.f);
        sr[3] = fmaxf(fmaf(dd, a3, bA.w), 0.f);
        sr[4] = fmaxf(fmaf(dd, a4, bB.x), 0.f);
        sr[5] = fmaxf(fmaf(dd, a5, bB.y), 0.f);
        sr[6] = fmaxf(fmaf(dd, a6, bB.z), 0.f);
        sr[7] = fmaxf(fmaf(dd, a7, bB.w), 0.f);
    }
    // same-wave LDS write->read: ordered, no barrier needed.
    // lane (eo,g): output feature g, k in {eo, eo+4, ..., eo+124}.
    const float* sr = srow[wave];
    float p = 0.f;
#pragma unroll 8
    for (int kk = 0; kk < 32; ++kk) {
        int k = eo + 4 * kk;
        p = fmaf(sr[k], sw2[k * OUT_DIM + g], p);
    }
    p += __shfl_xor(p, 16);
    p += __shfl_xor(p, 32);
    p *= dd;
    float pn = __shfl_xor(p, 1);   // feature g^1's value
    if (eo == 0 && (g & 1) == 0)
        h2s[(size_t)node * 8 + (g >> 1)] = packbf(p, pn);
}

// ===== layer-2 pull (bf16 rows, 16 edges/iter) + bias + log_softmax ========
// lane = eo*8 + g; eo in [0,8) edge slot, g in [0,8) feature pair (dword).
__global__ __launch_bounds__(256) void agg2_pull(const unsigned* __restrict__ h2s,
                                                 const float* __restrict__ dinv,
                                                 const float* __restrict__ b2,
                                                 const int* __restrict__ rowptr,
                                                 const int* __restrict__ ssrc,
                                                 float* __restrict__ out) {
    int wave = threadIdx.x >> 6;
    int lane = threadIdx.x & 63;
    int node = __builtin_amdgcn_readfirstlane(blockIdx.x * 4 + wave);
    if (node >= N_NODES) return;
    int eo = lane >> 3;
    int g  = lane & 7;

    int lo = rowptr[node], hi = rowptr[node + 1];
    float a0 = 0.f, a1 = 0.f;
    if (eo == 0) {
        unsigned u = h2s[(size_t)node * 8 + g];
        a0 = bflo(u); a1 = bfhi(u);
    }
    int e = lo;
    for (; e + 16 <= hi; e += 16) {
        int s0 = ssrc[e + eo];
        int s1 = ssrc[e + 8 + eo];
        unsigned u0 = h2s[(size_t)s0 * 8 + g];
        unsigned u1 = h2s[(size_t)s1 * 8 + g];
        a0 += bflo(u0); a1 += bfhi(u0);
        a0 += bflo(u1); a1 += bfhi(u1);
    }
    for (; e + 8 <= hi; e += 8) {
        int s = ssrc[e + eo];
        unsigned u = h2s[(size_t)s * 8 + g];
        a0 += bflo(u); a1 += bfhi(u);
    }
    if (eo < hi - e) {
        int s = ssrc[e + eo];
        unsigned u = h2s[(size_t)s * 8 + g];
        a0 += bflo(u); a1 += bfhi(u);
    }

    a0 += __shfl_xor(a0, 8);  a1 += __shfl_xor(a1, 8);
    a0 += __shfl_xor(a0, 16); a1 += __shfl_xor(a1, 16);
    a0 += __shfl_xor(a0, 32); a1 += __shfl_xor(a1, 32);

    float dd = dinv[node];
    float2 bb = *(const float2*)(b2 + 2 * g);
    float v0 = fmaf(dd, a0, bb.x);
    float v1 = fmaf(dd, a1, bb.y);

    float m = fmaxf(v0, v1);
#pragma unroll
    for (int msk = 1; msk < 8; msk <<= 1) m = fmaxf(m, __shfl_xor(m, msk));
    float s2 = __expf(v0 - m) + __expf(v1 - m);
#pragma unroll
    for (int msk = 1; msk < 8; msk <<= 1) s2 += __shfl_xor(s2, msk);
    float lse = m + __logf(s2);
    if (eo == 0) {
        float2 o; o.x = v0 - lse; o.y = v1 - lse;
        *(float2*)(out + (size_t)node * OUT_DIM + 2 * g) = o;
    }
}

extern "C" void kernel_launch(void* const* d_in, const int* in_sizes, int n_in,
                              void* d_out, int out_size, void* d_ws, size_t ws_size,
                              hipStream_t stream) {
    const float* x  = (const float*)d_in[0];
    const int*   ei = (const int*)d_in[1];
    const float* W1 = (const float*)d_in[2];
    const float* b1 = (const float*)d_in[3];
    const float* W2 = (const float*)d_in[4];
    const float* b2 = (const float*)d_in[5];
    float* out = (float*)d_out;

    const int n = N_NODES;
    const int e = E_EDGES;
    const int* srcp = ei;        // edge_index[0]
    const int* dstp = ei + e;    // edge_index[1]

    // workspace layout
    char* w = (char*)d_ws;
    int*      cnt_bb = (int*)w;        w += (size_t)NBUCK * NBLK * 4;
    int*      btot   = (int*)w;        w += (size_t)NBUCK * 4;
    int*      bbase  = (int*)w;        w += (size_t)(NBUCK + 1) * 4;
    int*      rowptr = (int*)w;        w += (size_t)(n + 1) * 4;
    float*    dinv   = (float*)w;      w += (size_t)n * 4;
    unsigned* tmp    = (unsigned*)w;   w += (size_t)e * 4;
    int*      ssrc   = (int*)w;        w += (size_t)e * 4;
    uint4*    wtf    = (uint4*)w;      w += (size_t)64 * 64 * 16;   // frag-major bf16 W1
    short*    h1s    = (short*)w;      w += (size_t)n * HID * 2;    // bf16, pre-scaled
    unsigned* h2s    = (unsigned*)w;   w += (size_t)n * 8 * 4;      // bf16 packed, 8 dw/node

    auto blk = [](long long total, int b) { return (int)((total + b - 1) / b); };

    // CSR build (bucketed counting sort; also produces rowptr + dinv);
    // W1 transpose piggybacks on the csr_b2 launch (independent blocks).
    csr_a<<<NBLK, 256, 0, stream>>>((const int4*)dstp, cnt_bb);
    csr_b1<<<NBUCK, NBLK, 0, stream>>>(cnt_bb, btot);
    csr_b2_w1t<<<9, 512, 0, stream>>>(btot, bbase, W1, wtf);
    csr_c<<<NBLK, 256, 0, stream>>>((const int4*)srcp, (const int4*)dstp, cnt_bb, bbase, tmp);
    csr_p2<<<NBUCK, 256, 0, stream>>>(tmp, bbase, rowptr, dinv, ssrc);

    // layer 1 GEMM + fused (aggregate1 + relu + layer-2 transform)
    gemm1_mfma<<<blk(n, 128), 512, 0, stream>>>(x, wtf, dinv, h1s);
    agg1_fused<<<blk(n, 4), 256, 0, stream>>>(h1s, dinv, b1, W2, rowptr, ssrc, h2s);

    // layer 2 aggregate + log_softmax
    agg2_pull<<<blk(n, 4), 256, 0, stream>>>(h2s, dinv, b2, rowptr, ssrc, out);
}

// Round 11
// 190.519 us; speedup vs baseline: 4.9623x; 1.0151x over previous
//
#include <hip/hip_runtime.h>
#include <hip/hip_bf16.h>

#define N_NODES 50000
#define E_EDGES 800000
#define IN_DIM  256
#define HID     128
#define OUT_DIM 16

#define NBUCK 391    // ceil(50000/128) buckets of 128 nodes (dst>>7)
#define NBLK  128    // blocks for bucket phases A/C
#define P2CAP 4096   // max edges per bucket (mean 2046, sigma ~45)

using frag_ab = __attribute__((ext_vector_type(8))) short;  // 8 bf16
using frag_cd = __attribute__((ext_vector_type(4))) float;  // 4 fp32

static __device__ inline short f2bf(float f) {
    union { float f; unsigned u; } v; v.f = f;
    unsigned r = (v.u + 0x7fffu + ((v.u >> 16) & 1u)) >> 16;
    return (short)r;
}
static __device__ inline float bflo(unsigned u) {
    union { unsigned u; float f; } v; v.u = u << 16; return v.f;
}
static __device__ inline float bfhi(unsigned u) {
    union { unsigned u; float f; } v; v.u = u & 0xffff0000u; return v.f;
}
static __device__ inline unsigned packbf(float a, float b) {
    return (unsigned)(unsigned short)f2bf(a) | ((unsigned)(unsigned short)f2bf(b) << 16);
}

// ================= CSR build: 2-level bucketed counting sort =================

__global__ __launch_bounds__(256) void csr_a(const int4* __restrict__ dst4,
                                             int* __restrict__ cnt_bb) {
    __shared__ int h[NBUCK];
    int t = threadIdx.x;
    for (int i = t; i < NBUCK; i += 256) h[i] = 0;
    __syncthreads();
    for (int i = blockIdx.x * 256 + t; i < E_EDGES / 4; i += NBLK * 256) {
        int4 d = dst4[i];
        atomicAdd(&h[d.x >> 7], 1);
        atomicAdd(&h[d.y >> 7], 1);
        atomicAdd(&h[d.z >> 7], 1);
        atomicAdd(&h[d.w >> 7], 1);
    }
    __syncthreads();
    for (int i = t; i < NBUCK; i += 256) cnt_bb[i * NBLK + blockIdx.x] = h[i];
}

__global__ __launch_bounds__(NBLK) void csr_b1(int* __restrict__ cnt_bb,
                                               int* __restrict__ btot) {
    __shared__ int sm[NBLK];
    int b = blockIdx.x, t = threadIdx.x;
    int v = cnt_bb[b * NBLK + t];
    sm[t] = v;
    __syncthreads();
    for (int o = 1; o < NBLK; o <<= 1) {
        int u = (t >= o) ? sm[t - o] : 0;
        __syncthreads();
        sm[t] += u;
        __syncthreads();
    }
    cnt_bb[b * NBLK + t] = sm[t] - v;
    if (t == NBLK - 1) btot[b] = sm[t];
}

// blocks 0..7: W1 -> fragment-major bf16; block 8: scan of btot;
// block 9: W2 -> column-major bf16 (w2t[n][k]).
__global__ __launch_bounds__(512) void csr_b2_w1t(const int* __restrict__ btot,
                                                  int* __restrict__ bbase,
                                                  const float* __restrict__ W,
                                                  uint4* __restrict__ wtf,
                                                  const float* __restrict__ W2,
                                                  short* __restrict__ w2t) {
    int t = threadIdx.x;
    if (blockIdx.x < 8) {
        int j = blockIdx.x * 512 + t;
        int f = j >> 6, lane = j & 63;
        int kt = f >> 3, tt = f & 7;
        int m = lane & 15, q = lane >> 4;
        int c = tt * 16 + m;
        int k0 = kt * 32 + q * 8;
        unsigned p[4];
#pragma unroll
        for (int i = 0; i < 4; ++i)
            p[i] = packbf(W[(k0 + 2 * i) * HID + c], W[(k0 + 2 * i + 1) * HID + c]);
        uint4 v; v.x = p[0]; v.y = p[1]; v.z = p[2]; v.w = p[3];
        wtf[j] = v;
        return;
    }
    if (blockIdx.x == 9) {
        int n0 = t >> 5, k0 = (t & 31) * 4;
#pragma unroll
        for (int i = 0; i < 4; ++i)
            w2t[n0 * HID + k0 + i] = f2bf(W2[(k0 + i) * OUT_DIM + n0]);
        return;
    }
    __shared__ int sm[512];
    int v = (t < NBUCK) ? btot[t] : 0;
    sm[t] = v;
    __syncthreads();
    for (int o = 1; o < 512; o <<= 1) {
        int u = (t >= o) ? sm[t - o] : 0;
        __syncthreads();
        sm[t] += u;
        __syncthreads();
    }
    if (t < NBUCK) bbase[t] = sm[t] - v;
    if (t == 511) bbase[NBUCK] = sm[511];
}

__global__ __launch_bounds__(256) void csr_c(const int4* __restrict__ src4,
                                             const int4* __restrict__ dst4,
                                             const int* __restrict__ cnt_bb,
                                             const int* __restrict__ bbase,
                                             unsigned* __restrict__ tmp) {
    __shared__ int run[NBUCK];
    int t = threadIdx.x;
    for (int i = t; i < NBUCK; i += 256)
        run[i] = bbase[i] + cnt_bb[i * NBLK + blockIdx.x];
    __syncthreads();
    for (int i = blockIdx.x * 256 + t; i < E_EDGES / 4; i += NBLK * 256) {
        int4 d = dst4[i];
        int4 s = src4[i];
        int p0 = atomicAdd(&run[d.x >> 7], 1);
        tmp[p0] = (unsigned)s.x | ((unsigned)(d.x & 127) << 17);
        int p1 = atomicAdd(&run[d.y >> 7], 1);
        tmp[p1] = (unsigned)s.y | ((unsigned)(d.y & 127) << 17);
        int p2 = atomicAdd(&run[d.z >> 7], 1);
        tmp[p2] = (unsigned)s.z | ((unsigned)(d.z & 127) << 17);
        int p3 = atomicAdd(&run[d.w >> 7], 1);
        tmp[p3] = (unsigned)s.w | ((unsigned)(d.w & 127) << 17);
    }
}

__global__ __launch_bounds__(256) void csr_p2(const unsigned* __restrict__ tmp,
                                              const int* __restrict__ bbase,
                                              int* __restrict__ rowptr,
                                              float* __restrict__ dinv,
                                              int* __restrict__ ssrc) {
    __shared__ unsigned ed[P2CAP];
    __shared__ int cnt[128];
    __shared__ int off[128];
    int b = blockIdx.x, t = threadIdx.x;
    int base = bbase[b];
    int m = bbase[b + 1] - base;
    if (m > P2CAP) m = P2CAP;
    if (t < 128) cnt[t] = 0;
    __syncthreads();
    for (int i = t; i < m; i += 256) {
        unsigned v = tmp[base + i];
        ed[i] = v;
        atomicAdd(&cnt[v >> 17], 1);
    }
    __syncthreads();
    if (t < 128) off[t] = cnt[t];
    __syncthreads();
    for (int o = 1; o < 128; o <<= 1) {
        int u = (t >= o && t < 128) ? off[t - o] : 0;
        __syncthreads();
        if (t < 128) off[t] += u;
        __syncthreads();
    }
    if (t < 128) {
        int node = b * 128 + t;
        int ex = off[t] - cnt[t];
        if (node < N_NODES) {
            rowptr[node] = base + ex;
            dinv[node] = rsqrtf((float)(cnt[t] + 1));
        }
        off[t] = ex;
    }
    if (b == NBUCK - 1 && t == 0) rowptr[N_NODES] = E_EDGES;
    __syncthreads();
    for (int i = t; i < m; i += 256) {
        unsigned v = ed[i];
        int p = atomicAdd(&off[v >> 17], 1);
        ssrc[base + p] = (int)(v & 0x1FFFF);
    }
}

// ================= layer-1 GEMM: LDS-staged B, bf16 MFMA ====================
__global__ __launch_bounds__(512) void gemm1_mfma(const float* __restrict__ x,
                                                  const uint4* __restrict__ wtf,
                                                  const float* __restrict__ dinv,
                                                  short* __restrict__ h) {
    __shared__ uint4 lwt[64 * 64];   // 64 KB
    int tid = threadIdx.x;
#pragma unroll
    for (int i = 0; i < 8; ++i)
        lwt[i * 512 + tid] = wtf[i * 512 + tid];

    int wave = tid >> 6;
    int lane = tid & 63;
    int m = lane & 15;
    int q = lane >> 4;
    int row0 = blockIdx.x * 128 + wave * 16;
    int arow_idx = row0 + m;
    const float4* arow4 = (const float4*)(x + (size_t)(arow_idx < N_NODES ? arow_idx : 0) * IN_DIM);

    frag_ab a[8];
#pragma unroll
    for (int kt = 0; kt < 8; ++kt) {
        float4 f0 = arow4[kt * 8 + q * 2];
        float4 f1 = arow4[kt * 8 + q * 2 + 1];
        a[kt][0] = f2bf(f0.x); a[kt][1] = f2bf(f0.y); a[kt][2] = f2bf(f0.z); a[kt][3] = f2bf(f0.w);
        a[kt][4] = f2bf(f1.x); a[kt][5] = f2bf(f1.y); a[kt][6] = f2bf(f1.z); a[kt][7] = f2bf(f1.w);
    }

    frag_cd acc[8];
#pragma unroll
    for (int t = 0; t < 8; ++t) acc[t] = frag_cd{0.f, 0.f, 0.f, 0.f};

    __syncthreads();

#pragma unroll
    for (int kt = 0; kt < 8; ++kt) {
#pragma unroll
        for (int t = 0; t < 8; ++t) {
            frag_ab b = *(const frag_ab*)&lwt[(kt * 8 + t) * 64 + lane];
            acc[t] = __builtin_amdgcn_mfma_f32_16x16x32_bf16(a[kt], b, acc[t], 0, 0, 0);
        }
    }

    float dv[4];
#pragma unroll
    for (int r = 0; r < 4; ++r) {
        int orow = row0 + q * 4 + r;
        dv[r] = (orow < N_NODES) ? dinv[orow] : 0.f;
    }
#pragma unroll
    for (int t = 0; t < 8; ++t) {
#pragma unroll
        for (int r = 0; r < 4; ++r) {
            int orow = row0 + q * 4 + r;
            if (orow < N_NODES)
                h[(size_t)orow * HID + t * 16 + m] = f2bf(acc[t][r] * dv[r]);
        }
    }
}

// ===== layer-1 pull: gather + reduce + bias/ReLU -> bf16 out1 (no LDS) =====
__global__ __launch_bounds__(256) void agg1_pull(const short* __restrict__ h1s,
                                                 const float* __restrict__ dinv,
                                                 const float* __restrict__ b1,
                                                 const int* __restrict__ rowptr,
                                                 const int* __restrict__ ssrc,
                                                 uint4* __restrict__ out1) {
    int wave = threadIdx.x >> 6;
    int lane = threadIdx.x & 63;
    int node = __builtin_amdgcn_readfirstlane(blockIdx.x * 4 + wave);
    if (node >= N_NODES) return;
    int eo = lane >> 4;       // edge slot in quad
    int g  = lane & 15;       // feature octet

    int lo = rowptr[node], hi = rowptr[node + 1];
    float dd = dinv[node];
    float a0 = 0.f, a1 = 0.f, a2 = 0.f, a3 = 0.f;
    float a4 = 0.f, a5 = 0.f, a6 = 0.f, a7 = 0.f;

    if (eo == 0) {   // self-loop row
        uint4 u = *(const uint4*)(h1s + (size_t)node * HID + g * 8);
        a0 = bflo(u.x); a1 = bfhi(u.x); a2 = bflo(u.y); a3 = bfhi(u.y);
        a4 = bflo(u.z); a5 = bfhi(u.z); a6 = bflo(u.w); a7 = bfhi(u.w);
    }

    int e = lo;
    for (; e + 16 <= hi; e += 16) {
        int s0 = ssrc[e + eo];
        int s1 = ssrc[e + 4 + eo];
        int s2 = ssrc[e + 8 + eo];
        int s3 = ssrc[e + 12 + eo];
        uint4 u0 = *(const uint4*)(h1s + (size_t)s0 * HID + g * 8);
        uint4 u1 = *(const uint4*)(h1s + (size_t)s1 * HID + g * 8);
        uint4 u2 = *(const uint4*)(h1s + (size_t)s2 * HID + g * 8);
        uint4 u3 = *(const uint4*)(h1s + (size_t)s3 * HID + g * 8);
        a0 += bflo(u0.x); a1 += bfhi(u0.x); a2 += bflo(u0.y); a3 += bfhi(u0.y);
        a4 += bflo(u0.z); a5 += bfhi(u0.z); a6 += bflo(u0.w); a7 += bfhi(u0.w);
        a0 += bflo(u1.x); a1 += bfhi(u1.x); a2 += bflo(u1.y); a3 += bfhi(u1.y);
        a4 += bflo(u1.z); a5 += bfhi(u1.z); a6 += bflo(u1.w); a7 += bfhi(u1.w);
        a0 += bflo(u2.x); a1 += bfhi(u2.x); a2 += bflo(u2.y); a3 += bfhi(u2.y);
        a4 += bflo(u2.z); a5 += bfhi(u2.z); a6 += bflo(u2.w); a7 += bfhi(u2.w);
        a0 += bflo(u3.x); a1 += bfhi(u3.x); a2 += bflo(u3.y); a3 += bfhi(u3.y);
        a4 += bflo(u3.z); a5 += bfhi(u3.z); a6 += bflo(u3.w); a7 += bfhi(u3.w);
    }
    for (; e + 4 <= hi; e += 4) {
        int s = ssrc[e + eo];
        uint4 u = *(const uint4*)(h1s + (size_t)s * HID + g * 8);
        a0 += bflo(u.x); a1 += bfhi(u.x); a2 += bflo(u.y); a3 += bfhi(u.y);
        a4 += bflo(u.z); a5 += bfhi(u.z); a6 += bflo(u.w); a7 += bfhi(u.w);
    }
    if (eo < hi - e) {
        int s = ssrc[e + eo];
        uint4 u = *(const uint4*)(h1s + (size_t)s * HID + g * 8);
        a0 += bflo(u.x); a1 += bfhi(u.x); a2 += bflo(u.y); a3 += bfhi(u.y);
        a4 += bflo(u.z); a5 += bfhi(u.z); a6 += bflo(u.w); a7 += bfhi(u.w);
    }

    a0 += __shfl_xor(a0, 16); a1 += __shfl_xor(a1, 16);
    a2 += __shfl_xor(a2, 16); a3 += __shfl_xor(a3, 16);
    a4 += __shfl_xor(a4, 16); a5 += __shfl_xor(a5, 16);
    a6 += __shfl_xor(a6, 16); a7 += __shfl_xor(a7, 16);
    a0 += __shfl_xor(a0, 32); a1 += __shfl_xor(a1, 32);
    a2 += __shfl_xor(a2, 32); a3 += __shfl_xor(a3, 32);
    a4 += __shfl_xor(a4, 32); a5 += __shfl_xor(a5, 32);
    a6 += __shfl_xor(a6, 32); a7 += __shfl_xor(a7, 32);

    if (eo == 0) {
        float4 bA = *(const float4*)(b1 + g * 8);
        float4 bB = *(const float4*)(b1 + g * 8 + 4);
        float o0 = fmaxf(fmaf(dd, a0, bA.x), 0.f);
        float o1 = fmaxf(fmaf(dd, a1, bA.y), 0.f);
        float o2 = fmaxf(fmaf(dd, a2, bA.z), 0.f);
        float o3 = fmaxf(fmaf(dd, a3, bA.w), 0.f);
        float o4 = fmaxf(fmaf(dd, a4, bB.x), 0.f);
        float o5 = fmaxf(fmaf(dd, a5, bB.y), 0.f);
        float o6 = fmaxf(fmaf(dd, a6, bB.z), 0.f);
        float o7 = fmaxf(fmaf(dd, a7, bB.w), 0.f);
        uint4 st;
        st.x = packbf(o0, o1); st.y = packbf(o2, o3);
        st.z = packbf(o4, o5); st.w = packbf(o6, o7);
        out1[(size_t)node * 16 + g] = st;
    }
}

// ===== layer-2 transform via MFMA: h2s = (out1 @ W2) * dinv, bf16 out ======
__global__ __launch_bounds__(256) void gemm2_mfma(const short* __restrict__ out1,
                                                  const short* __restrict__ w2t,
                                                  const float* __restrict__ dinv,
                                                  short* __restrict__ h2s) {
    int wave = threadIdx.x >> 6;
    int lane = threadIdx.x & 63;
    int m = lane & 15;
    int q = lane >> 4;
    int row0 = blockIdx.x * 64 + wave * 16;
    int arow = row0 + m;
    if (arow >= N_NODES) arow = N_NODES - 1;   // clamp loads
    const short* ap = out1 + (size_t)arow * HID + q * 8;
    const short* bp = w2t + m * HID + q * 8;

    frag_cd acc = frag_cd{0.f, 0.f, 0.f, 0.f};
#pragma unroll
    for (int kt = 0; kt < 4; ++kt) {
        frag_ab a = *(const frag_ab*)(ap + kt * 32);
        frag_ab b = *(const frag_ab*)(bp + kt * 32);
        acc = __builtin_amdgcn_mfma_f32_16x16x32_bf16(a, b, acc, 0, 0, 0);
    }
#pragma unroll
    for (int r = 0; r < 4; ++r) {
        int row = row0 + q * 4 + r;
        if (row < N_NODES)
            h2s[(size_t)row * OUT_DIM + m] = f2bf(acc[r] * dinv[row]);
    }
}

// ===== layer-2 pull (bf16 rows, 16 edges/iter) + bias + log_softmax ========
__global__ __launch_bounds__(256) void agg2_pull(const unsigned* __restrict__ h2s,
                                                 const float* __restrict__ dinv,
                                                 const float* __restrict__ b2,
                                                 const int* __restrict__ rowptr,
                                                 const int* __restrict__ ssrc,
                                                 float* __restrict__ out) {
    int wave = threadIdx.x >> 6;
    int lane = threadIdx.x & 63;
    int node = __builtin_amdgcn_readfirstlane(blockIdx.x * 4 + wave);
    if (node >= N_NODES) return;
    int eo = lane >> 3;
    int g  = lane & 7;

    int lo = rowptr[node], hi = rowptr[node + 1];
    float a0 = 0.f, a1 = 0.f;
    if (eo == 0) {
        unsigned u = h2s[(size_t)node * 8 + g];
        a0 = bflo(u); a1 = bfhi(u);
    }
    int e = lo;
    for (; e + 16 <= hi; e += 16) {
        int s0 = ssrc[e + eo];
        int s1 = ssrc[e + 8 + eo];
        unsigned u0 = h2s[(size_t)s0 * 8 + g];
        unsigned u1 = h2s[(size_t)s1 * 8 + g];
        a0 += bflo(u0); a1 += bfhi(u0);
        a0 += bflo(u1); a1 += bfhi(u1);
    }
    for (; e + 8 <= hi; e += 8) {
        int s = ssrc[e + eo];
        unsigned u = h2s[(size_t)s * 8 + g];
        a0 += bflo(u); a1 += bfhi(u);
    }
    if (eo < hi - e) {
        int s = ssrc[e + eo];
        unsigned u = h2s[(size_t)s * 8 + g];
        a0 += bflo(u); a1 += bfhi(u);
    }

    a0 += __shfl_xor(a0, 8);  a1 += __shfl_xor(a1, 8);
    a0 += __shfl_xor(a0, 16); a1 += __shfl_xor(a1, 16);
    a0 += __shfl_xor(a0, 32); a1 += __shfl_xor(a1, 32);

    float dd = dinv[node];
    float2 bb = *(const float2*)(b2 + 2 * g);
    float v0 = fmaf(dd, a0, bb.x);
    float v1 = fmaf(dd, a1, bb.y);

    float m = fmaxf(v0, v1);
#pragma unroll
    for (int msk = 1; msk < 8; msk <<= 1) m = fmaxf(m, __shfl_xor(m, msk));
    float s2 = __expf(v0 - m) + __expf(v1 - m);
#pragma unroll
    for (int msk = 1; msk < 8; msk <<= 1) s2 += __shfl_xor(s2, msk);
    float lse = m + __logf(s2);
    if (eo == 0) {
        float2 o; o.x = v0 - lse; o.y = v1 - lse;
        *(float2*)(out + (size_t)node * OUT_DIM + 2 * g) = o;
    }
}

extern "C" void kernel_launch(void* const* d_in, const int* in_sizes, int n_in,
                              void* d_out, int out_size, void* d_ws, size_t ws_size,
                              hipStream_t stream) {
    const float* x  = (const float*)d_in[0];
    const int*   ei = (const int*)d_in[1];
    const float* W1 = (const float*)d_in[2];
    const float* b1 = (const float*)d_in[3];
    const float* W2 = (const float*)d_in[4];
    const float* b2 = (const float*)d_in[5];
    float* out = (float*)d_out;

    const int n = N_NODES;
    const int e = E_EDGES;
    const int* srcp = ei;        // edge_index[0]
    const int* dstp = ei + e;    // edge_index[1]

    // workspace layout
    char* w = (char*)d_ws;
    int*      cnt_bb = (int*)w;        w += (size_t)NBUCK * NBLK * 4;
    int*      btot   = (int*)w;        w += (size_t)NBUCK * 4;
    int*      bbase  = (int*)w;        w += (size_t)(NBUCK + 1) * 4;
    int*      rowptr = (int*)w;        w += (size_t)(n + 1) * 4;
    float*    dinv   = (float*)w;      w += (size_t)n * 4;
    unsigned* tmp    = (unsigned*)w;   w += (size_t)e * 4;
    int*      ssrc   = (int*)w;        w += (size_t)e * 4;
    uint4*    wtf    = (uint4*)w;      w += (size_t)64 * 64 * 16;   // frag-major bf16 W1
    short*    w2t    = (short*)w;      w += (size_t)OUT_DIM * HID * 2;  // col-major bf16 W2
    short*    h1s    = (short*)w;      w += (size_t)n * HID * 2;    // bf16, pre-scaled
    short*    out1   = (short*)w;      w += (size_t)n * HID * 2;    // bf16 relu'd layer-1 out
    short*    h2s    = (short*)w;      w += (size_t)n * OUT_DIM * 2; // bf16

    auto blk = [](long long total, int b) { return (int)((total + b - 1) / b); };

    // CSR build (bucketed counting sort; also produces rowptr + dinv);
    // W1/W2 transposes piggyback on the csr_b2 launch (independent blocks).
    csr_a<<<NBLK, 256, 0, stream>>>((const int4*)dstp, cnt_bb);
    csr_b1<<<NBUCK, NBLK, 0, stream>>>(cnt_bb, btot);
    csr_b2_w1t<<<10, 512, 0, stream>>>(btot, bbase, W1, wtf, W2, w2t);
    csr_c<<<NBLK, 256, 0, stream>>>((const int4*)srcp, (const int4*)dstp, cnt_bb, bbase, tmp);
    csr_p2<<<NBUCK, 256, 0, stream>>>(tmp, bbase, rowptr, dinv, ssrc);

    // layer 1
    gemm1_mfma<<<blk(n, 128), 512, 0, stream>>>(x, wtf, dinv, h1s);
    agg1_pull<<<blk(n, 4), 256, 0, stream>>>(h1s, dinv, b1, rowptr, ssrc, (uint4*)out1);

    // layer 2
    gemm2_mfma<<<blk(n, 64), 256, 0, stream>>>(out1, w2t, dinv, h2s);
    agg2_pull<<<blk(n, 4), 256, 0, stream>>>((const unsigned*)h2s, dinv, b2, rowptr, ssrc, out);
}